// Round 2
// baseline (7995.672 us; speedup 1.0000x reference)
//
#include <hip/hip_runtime.h>
#include <hip/hip_fp16.h>
#include <cstdint>

typedef float f4 __attribute__((ext_vector_type(4)));
typedef unsigned long long u64;

// Problem constants
// B=32, F=34, T=1000, K=7, S=3, F_DOWN=10, C=64, H=640, 3H=1920, T_MAX=9, PAD=4, MS_KS=200

// ---------------------------------------------------------------------------
// K1: build DCLS kernel dk[h][i][tau], h<640, i<14, tau<9
__global__ void k_dk(const float* __restrict__ dcls_w, const float* __restrict__ dcls_p,
                     float* __restrict__ dk) {
    int idx = blockIdx.x * 256 + threadIdx.x;
    if (idx >= 640 * 126) return;
    int h = idx / 126;
    int r = idx % 126;
    int i = r / 9;
    int tau = r % 9;
    float p = dcls_p[h * 14 + i];
    p = fminf(fmaxf(p, 0.f), 8.f);
    float tri = fmaxf(1.f - fabsf((float)tau - p), 0.f);
    dk[idx] = dcls_w[h * 14 + i] * tri;
}

// ---------------------------------------------------------------------------
// K2: EMA lowpass (200-tap truncated, exact) + highpass. hp[b][f][t]
__global__ void k_ema(const float* __restrict__ x, const float* __restrict__ a_vals,
                      const float* __restrict__ w_vals, float* __restrict__ hp) {
    __shared__ float xr[1024];
    int bf = blockIdx.x;               // b*34+f
    int f = bf % 34;
    int tid = threadIdx.x;
    const float* xs = x + (size_t)bf * 1000;
    for (int i = tid; i < 1000; i += 256) xr[i] = xs[i];
    for (int i = 1000 + tid; i < 1024; i += 256) xr[i] = 0.f;
    __syncthreads();
    float a = a_vals[f], wv = w_vals[f];
    float om = 1.f - a;
    int t1 = tid, t2 = tid + 256, t3 = tid + 512, t4 = tid + 768;
    bool v4 = (t4 < 1000);
    float a0 = 0.f, a1 = 0.f, a2 = 0.f, a3 = 0.f;
    float coef = a;
    for (int k = 0; k < 200; ++k) {
        a0 += (k <= t1 ? xr[t1 - k] : 0.f) * coef;
        a1 += xr[t2 - k] * coef;
        a2 += xr[t3 - k] * coef;
        a3 += (v4 ? xr[t4 - k] : 0.f) * coef;
        coef *= om;
    }
    float* op = hp + (size_t)bf * 1000;
    op[t1] = xr[t1] - wv * a0;
    op[t2] = xr[t2] - wv * a1;
    op[t3] = xr[t3] - wv * a2;
    if (v4) op[t4] = xr[t4] - wv * a3;
}

// ---------------------------------------------------------------------------
// K3: DCLS grouped conv. ybcgt[b][h=c*10+g][t] = bias[g*64+c] + sum_{i,tau} u * dk
__global__ void __launch_bounds__(256) k_conv(const float* __restrict__ hp,
                                              const float* __restrict__ dk,
                                              const float* __restrict__ dcls_b,
                                              float* __restrict__ ybcgt) {
    __shared__ float u[2 * 7 * 264];    // [pm][kk][264]
    __shared__ float dks[64 * 126];
    int tid = threadIdx.x;
    int t0 = blockIdx.x * 256;
    int g = blockIdx.y;
    int b = blockIdx.z;
    for (int idx = tid; idx < 8064; idx += 256) dks[idx] = dk[g * 8064 + idx];
    for (int idx = tid; idx < 3696; idx += 256) {
        int pm = idx / 1848;
        int rem = idx % 1848;
        int kk = rem / 264;
        int tt = rem % 264;
        int tg = t0 - 4 + tt;
        float v = (tg >= 0 && tg < 1000) ? hp[((size_t)(b * 34 + g * 3 + kk)) * 1000 + tg] : 0.f;
        u[idx] = pm ? fmaxf(-v, 0.f) : fmaxf(v, 0.f);
    }
    __syncthreads();
    int tl = tid & 63;
    int cg4 = tid >> 6;     // 0..3, c = cg4*16+ci
    float acc[16][4];
#pragma unroll
    for (int ci = 0; ci < 16; ++ci)
#pragma unroll
        for (int tq = 0; tq < 4; ++tq) acc[ci][tq] = 0.f;

    for (int i = 0; i < 14; ++i) {
#pragma unroll
        for (int tau = 0; tau < 9; ++tau) {
            const float* ub = u + i * 264 + tl + tau;
            float u0 = ub[0];
            float u1 = ub[64];
            float u2 = ub[128];
            float u3 = ub[192];
            const float* dp = dks + cg4 * 16 * 126 + i * 9 + tau;
#pragma unroll
            for (int ci = 0; ci < 16; ++ci) {
                float dv = dp[ci * 126];
                acc[ci][0] += u0 * dv;
                acc[ci][1] += u1 * dv;
                acc[ci][2] += u2 * dv;
                acc[ci][3] += u3 * dv;
            }
        }
    }
#pragma unroll
    for (int ci = 0; ci < 16; ++ci) {
        int c = cg4 * 16 + ci;
        float bias = dcls_b[g * 64 + c];
        size_t base = ((size_t)(b * 640 + c * 10 + g)) * 1000;
#pragma unroll
        for (int tq = 0; tq < 4; ++tq) {
            int t = t0 + tq * 64 + tl;
            if (t < 1000) ybcgt[base + t] = acc[ci][tq] + bias;
        }
    }
}

// ---------------------------------------------------------------------------
// K4: BN stats: per channel c sum & sumsq over (b,g,t). bnsum[0..63]=sum, [64..127]=sumsq
__global__ void k_bnstat(const float* __restrict__ ybcgt, float* __restrict__ bnsum) {
    int c = blockIdx.x / 10;
    int g = blockIdx.x % 10;
    int tid = threadIdx.x;
    float s = 0.f, q = 0.f;
    const float* base = ybcgt + ((size_t)(c * 10 + g)) * 1000;
    for (int b = 0; b < 32; ++b) {
        const float* p = base + (size_t)b * 640000;
        for (int t = tid; t < 1000; t += 256) {
            float v = p[t];
            s += v;
            q += v * v;
        }
    }
    for (int off = 1; off < 64; off <<= 1) {
        s += __shfl_xor(s, off);
        q += __shfl_xor(q, off);
    }
    __shared__ float rs[4], rq[4];
    if ((tid & 63) == 0) { rs[tid >> 6] = s; rq[tid >> 6] = q; }
    __syncthreads();
    if (tid == 0) {
        s = rs[0] + rs[1] + rs[2] + rs[3];
        q = rq[0] + rq[1] + rq[2] + rq[3];
        atomicAdd(&bnsum[c], s);
        atomicAdd(&bnsum[64 + c], q);
    }
}

// K5: BN finalize -> bnp[c]=scale, bnp[64+c]=shift
__global__ void k_bnfin(const float* __restrict__ bnsum, const float* __restrict__ gamma,
                        const float* __restrict__ beta, float* __restrict__ bnp) {
    int c = threadIdx.x;
    const float inv_n = 1.f / 320000.f;
    float mean = bnsum[c] * inv_n;
    float var = bnsum[64 + c] * inv_n - mean * mean;
    float sc = gamma[c] * rsqrtf(var + 1e-5f);
    bnp[c] = sc;
    bnp[64 + c] = beta[c] - mean * sc;
}

// ---------------------------------------------------------------------------
// K6: fused transpose + BN + sigmoid: seq[(t*32+b)*640 + h] = sigmoid(scale*y + shift) (fp16)
__global__ void k_tr(const float* __restrict__ ybcgt, const float* __restrict__ bnp,
                     __half* __restrict__ seq) {
    __shared__ float tile[64 * 65];
    int tid = threadIdx.x;
    int tt0 = blockIdx.x * 64;
    int h0 = blockIdx.y * 64;
    int b = blockIdx.z;
    int tx = tid & 63;
    int ty = tid >> 6;
#pragma unroll
    for (int r = 0; r < 16; ++r) {
        int hh = r * 4 + ty;
        int t = tt0 + tx;
        float v = (t < 1000) ? ybcgt[((size_t)(b * 640 + h0 + hh)) * 1000 + t] : 0.f;
        int c = (h0 + hh) / 10;
        float sarg = bnp[c] * v + bnp[64 + c];
        tile[hh * 65 + tx] = 1.f / (1.f + __expf(-sarg));
    }
    __syncthreads();
#pragma unroll
    for (int r = 0; r < 16; ++r) {
        int t = tt0 + r * 4 + ty;
        if (t < 1000)
            seq[((size_t)t * 32 + b) * 640 + h0 + tx] = __float2half(tile[tx * 65 + r * 4 + ty]);
    }
}

// ---------------------------------------------------------------------------
// K7: x_proj GEMM (unchanged, passing): BM=BN=128, BK=8, 256 thr, 8x8 micro,
// 16 NAMED f4 accs; __launch_bounds__(256,4); Bs swizzled to break bank alias.
#define BCOL(c) ((c) + (((c) >> 5) << 2))
__global__ void __launch_bounds__(256, 4) k_gemm(const __half* __restrict__ A,
                                                 const float* __restrict__ W,
                                                 const float* __restrict__ bih,
                                                 __half* __restrict__ C) {
    __shared__ float As[8][128];
    __shared__ float Bs[8][140];
    int tid = threadIdx.x;
    int n0 = blockIdx.x * 128;
    int m0 = blockIdx.y * 128;
    int tx = tid & 15;          // n-subtile: cols n0 + tx*8 .. +7
    int ty = tid >> 4;          // m-subtile: rows m0 + ty*8 .. +7
    int lm = tid >> 1;
    int lk4 = (tid & 1) * 4;
    int lmB = BCOL(lm);
    const int bc0 = BCOL(tx * 8);
    const int bc1 = BCOL(tx * 8 + 4);
    const __half* Ab = A + (size_t)(m0 + lm) * 640 + lk4;
    const float* Bb = W + (size_t)(n0 + lm) * 640 + lk4;

    f4 c0a = {0,0,0,0}, c0b = {0,0,0,0}, c1a = {0,0,0,0}, c1b = {0,0,0,0};
    f4 c2a = {0,0,0,0}, c2b = {0,0,0,0}, c3a = {0,0,0,0}, c3b = {0,0,0,0};
    f4 c4a = {0,0,0,0}, c4b = {0,0,0,0}, c5a = {0,0,0,0}, c5b = {0,0,0,0};
    f4 c6a = {0,0,0,0}, c6b = {0,0,0,0}, c7a = {0,0,0,0}, c7b = {0,0,0,0};

    for (int kt = 0; kt < 80; ++kt) {
        float2 araw = *(const float2*)(Ab + (size_t)kt * 8);   // 4 halves
        const __half2* ah = (const __half2*)&araw;
        float2 a01 = __half22float2(ah[0]);
        float2 a23 = __half22float2(ah[1]);
        float4 bv = *(const float4*)(Bb + (size_t)kt * 8);
        __syncthreads();
        As[lk4 + 0][lm] = a01.x; As[lk4 + 1][lm] = a01.y;
        As[lk4 + 2][lm] = a23.x; As[lk4 + 3][lm] = a23.y;
        Bs[lk4 + 0][lmB] = bv.x; Bs[lk4 + 1][lmB] = bv.y;
        Bs[lk4 + 2][lmB] = bv.z; Bs[lk4 + 3][lmB] = bv.w;
        __syncthreads();
#pragma unroll
        for (int kk = 0; kk < 8; ++kk) {
            f4 blo = *(const f4*)&Bs[kk][bc0];
            f4 bhi = *(const f4*)&Bs[kk][bc1];
            f4 alo = *(const f4*)&As[kk][ty * 8];
            f4 ahi = *(const f4*)&As[kk][ty * 8 + 4];
            c0a += alo.x * blo; c0b += alo.x * bhi;
            c1a += alo.y * blo; c1b += alo.y * bhi;
            c2a += alo.z * blo; c2b += alo.z * bhi;
            c3a += alo.w * blo; c3b += alo.w * bhi;
            c4a += ahi.x * blo; c4b += ahi.x * bhi;
            c5a += ahi.y * blo; c5b += ahi.y * bhi;
            c6a += ahi.z * blo; c6b += ahi.z * bhi;
            c7a += ahi.w * blo; c7b += ahi.w * bhi;
        }
    }
    f4 bblo = *(const f4*)&bih[n0 + tx * 8];
    f4 bbhi = *(const f4*)&bih[n0 + tx * 8 + 4];
    union { __half h[8]; float4 v; } ob;
#define STORE_ROW(i, ra, rb)                                                     \
    {                                                                            \
        f4 lo = ra + bblo; f4 hi = rb + bbhi;                                    \
        ob.h[0] = __float2half(lo.x); ob.h[1] = __float2half(lo.y);              \
        ob.h[2] = __float2half(lo.z); ob.h[3] = __float2half(lo.w);              \
        ob.h[4] = __float2half(hi.x); ob.h[5] = __float2half(hi.y);              \
        ob.h[6] = __float2half(hi.z); ob.h[7] = __float2half(hi.w);              \
        *(float4*)&C[(size_t)(m0 + ty * 8 + i) * 1920 + n0 + tx * 8] = ob.v;     \
    }
    STORE_ROW(0, c0a, c0b) STORE_ROW(1, c1a, c1b) STORE_ROW(2, c2a, c2b)
    STORE_ROW(3, c3a, c3b) STORE_ROW(4, c4a, c4b) STORE_ROW(5, c5a, c5b)
    STORE_ROW(6, c6a, c6b) STORE_ROW(7, c7a, c7b)
#undef STORE_ROW
}

// ---------------------------------------------------------------------------
// K8 v2: batch-cohort pipelined persistent GRU.
// The B=32 batch chains are independent; split into cohorts A=b[0..15],
// B=b[16..31], each with its own h double-buffer and barrier line-set.
// Per step t: half-A then half-B. Cohort X's h exchange (store->L3, barrier,
// reload) is hidden under cohort Y's matvec+epilogue. Poll runs on wave 1
// (tid==64) concurrently with wave 0's epilogue; poll target is one half-step
// stale -> expected to hit on first read.
// Decomposition per half (512 thr): ksx=tid>>4 (32-way k split, 20 iters),
// jj=(tid>>2)&3 (j-local), bg=tid&3 (4 batches each). 12 accumulators.
// Reduction: shfl_xor 16/32 within wave -> red[8][16][12] -> wave-0 epilogue.
// hgu layout: [A0 | A1 | B0 | B1] x 2560 u64 (4 packed fp16 per u64).
// h_X(t) stored to parity (t+1)&1; h_X(t-1) read from parity t&1.
// Barrier math: each block +1 per half; poll target 160*(completed halves).
#define GRU_HALF(XR, XZ, XN, HOLD, STAGEP, POLLBASE, POLLTGT, STOREP, ARRBASE, COH16, FCOFF)        \
    {                                                                                               \
        float ar0 = 0.f, ar1 = 0.f, ar2 = 0.f, ar3 = 0.f;                                           \
        float az0 = 0.f, az1 = 0.f, az2 = 0.f, az3 = 0.f;                                           \
        float an0 = 0.f, an1 = 0.f, an2 = 0.f, an3 = 0.f;                                           \
        _Pragma("unroll 4")                                                                         \
        for (int ii = 0; ii < 20; ++ii) {                                                           \
            int k = ii * 32 + ksx;                                                                  \
            float4 wv = *(const float4*)(w_lds + k * 16 + jj * 4);                                  \
            float4 hv = *(const float4*)(h_lds + k * 16 + bg * 4);                                  \
            ar0 += wv.x * hv.x; ar1 += wv.x * hv.y; ar2 += wv.x * hv.z; ar3 += wv.x * hv.w;         \
            az0 += wv.y * hv.x; az1 += wv.y * hv.y; az2 += wv.y * hv.z; az3 += wv.y * hv.w;         \
            an0 += wv.z * hv.x; an1 += wv.z * hv.y; an2 += wv.z * hv.z; an3 += wv.z * hv.w;         \
        }                                                                                           \
        ar0 += __shfl_xor(ar0, 16); ar0 += __shfl_xor(ar0, 32);                                     \
        ar1 += __shfl_xor(ar1, 16); ar1 += __shfl_xor(ar1, 32);                                     \
        ar2 += __shfl_xor(ar2, 16); ar2 += __shfl_xor(ar2, 32);                                     \
        ar3 += __shfl_xor(ar3, 16); ar3 += __shfl_xor(ar3, 32);                                     \
        az0 += __shfl_xor(az0, 16); az0 += __shfl_xor(az0, 32);                                     \
        az1 += __shfl_xor(az1, 16); az1 += __shfl_xor(az1, 32);                                     \
        az2 += __shfl_xor(az2, 16); az2 += __shfl_xor(az2, 32);                                     \
        az3 += __shfl_xor(az3, 16); az3 += __shfl_xor(az3, 32);                                     \
        an0 += __shfl_xor(an0, 16); an0 += __shfl_xor(an0, 32);                                     \
        an1 += __shfl_xor(an1, 16); an1 += __shfl_xor(an1, 32);                                     \
        an2 += __shfl_xor(an2, 16); an2 += __shfl_xor(an2, 32);                                     \
        an3 += __shfl_xor(an3, 16); an3 += __shfl_xor(an3, 32);                                     \
        __syncthreads();                                                                            \
        if (lane < 16) {                                                                            \
            float* rp = red + (wid * 16 + lane) * 12;                                               \
            rp[0] = ar0; rp[1] = ar1; rp[2] = ar2;  rp[3] = ar3;                                    \
            rp[4] = az0; rp[5] = az1; rp[6] = az2;  rp[7] = az3;                                    \
            rp[8] = an0; rp[9] = an1; rp[10] = an2; rp[11] = an3;                                   \
        }                                                                                           \
        __syncthreads();                                                                            \
        if (tid < 64) {                                                                             \
            float hr = bh_r, hz = bh_z, hn = bh_n;                                                  \
            int ri = ej * 4 + (eb >> 2), bi = eb & 3;                                               \
            _Pragma("unroll")                                                                       \
            for (int w2 = 0; w2 < 8; ++w2) {                                                        \
                const float* rp = red + (w2 * 16 + ri) * 12 + bi;                                   \
                hr += rp[0]; hz += rp[4]; hn += rp[8];                                              \
            }                                                                                       \
            float r_ = 1.f / (1.f + __expf(-((XR) + hr)));                                          \
            float z_ = 1.f / (1.f + __expf(-((XZ) + hz)));                                          \
            float pre = (XN) + r_ * hn;                                                             \
            float e2 = __expf(-2.f * fabsf(pre));                                                   \
            float tn = (1.f - e2) / (1.f + e2);                                                     \
            float n_ = (pre >= 0.f) ? tn : -tn;                                                     \
            float hnew = (1.f - z_) * n_ + z_ * (HOLD);                                             \
            (HOLD) = hnew;                                                                          \
            float h1v = __shfl_xor(hnew, 1);                                                        \
            float lo_f = (eb & 1) ? h1v : hnew;                                                     \
            float hi_f = (eb & 1) ? hnew : h1v;                                                     \
            __half2 v2 = __floats2half2_rn(lo_f, hi_f);                                             \
            union { __half2 h2; unsigned u; } cv;                                                   \
            cv.h2 = v2;                                                                             \
            unsigned pa = cv.u;                                                                     \
            unsigned pb = (unsigned)__shfl_xor((int)pa, 2);                                         \
            u64 pku = ((eb & 2) == 0) ? ((u64)pa | ((u64)pb << 32))                                 \
                                      : ((u64)pb | ((u64)pa << 32));                                \
            if ((eb & 3) == 0)                                                                      \
                __hip_atomic_store(&(STOREP)[(j0 + ej) * 4 + (eb >> 2)], pku,                       \
                                   __ATOMIC_RELAXED, __HIP_MEMORY_SCOPE_AGENT);                     \
            fcred[tid] = hnew * fw;                                                                 \
            __builtin_amdgcn_s_waitcnt(0);                                                          \
            if (tid == 0)                                                                           \
                __hip_atomic_fetch_add(&(ARRBASE)[(blk & 7) * 32], 1u,                              \
                                       __ATOMIC_RELAXED, __HIP_MEMORY_SCOPE_AGENT);                 \
        } else if (tid == 64 && (POLLTGT) > 0u) {                                                   \
            for (;;) {                                                                              \
                unsigned s_ = 0;                                                                    \
                _Pragma("unroll")                                                                   \
                for (int i = 0; i < 8; ++i)                                                         \
                    s_ += __hip_atomic_load(&(POLLBASE)[i * 32], __ATOMIC_RELAXED,                  \
                                            __HIP_MEMORY_SCOPE_AGENT);                              \
                if (s_ >= (POLLTGT)) break;                                                         \
                __builtin_amdgcn_s_sleep(1);                                                        \
            }                                                                                       \
        }                                                                                           \
        __syncthreads();                                                                            \
        __atomic_signal_fence(__ATOMIC_SEQ_CST);                                                    \
        u64 rr0 = __hip_atomic_load(&(STAGEP)[tid],        __ATOMIC_RELAXED, __HIP_MEMORY_SCOPE_AGENT); \
        u64 rr1 = __hip_atomic_load(&(STAGEP)[512 + tid],  __ATOMIC_RELAXED, __HIP_MEMORY_SCOPE_AGENT); \
        u64 rr2 = __hip_atomic_load(&(STAGEP)[1024 + tid], __ATOMIC_RELAXED, __HIP_MEMORY_SCOPE_AGENT); \
        u64 rr3 = __hip_atomic_load(&(STAGEP)[1536 + tid], __ATOMIC_RELAXED, __HIP_MEMORY_SCOPE_AGENT); \
        u64 rr4 = __hip_atomic_load(&(STAGEP)[2048 + tid], __ATOMIC_RELAXED, __HIP_MEMORY_SCOPE_AGENT); \
        if (tid < 16) {                                                                             \
            float s_ = fcred[tid] + fcred[16 + tid] + fcred[32 + tid] + fcred[48 + tid];            \
            __hip_atomic_store(&fcpart[(size_t)blk * 32000 + t * 32 + (FCOFF) + tid], s_,           \
                               __ATOMIC_RELAXED, __HIP_MEMORY_SCOPE_AGENT);                         \
        }                                                                                           \
        if (tid < 64 && t + 1 < 1000) {                                                             \
            const __half* xpt = xp + ((size_t)(t + 1) * 32 + (COH16) + eb) * 1920;                  \
            int j = j0 + ej;                                                                        \
            (XR) = __half2float(xpt[j]);                                                            \
            (XZ) = __half2float(xpt[640 + j]);                                                      \
            (XN) = __half2float(xpt[1280 + j]);                                                     \
        }                                                                                           \
        {                                                                                           \
            union { u64 u; __half2 h2[2]; } pk;                                                     \
            pk.u = rr0; { int e = tid;        float2 lo = __half22float2(pk.h2[0]); float2 hi = __half22float2(pk.h2[1]); f4 v = {lo.x, lo.y, hi.x, hi.y}; *(f4*)&h_lds[(e >> 2) * 16 + (e & 3) * 4] = v; } \
            pk.u = rr1; { int e = 512 + tid;  float2 lo = __half22float2(pk.h2[0]); float2 hi = __half22float2(pk.h2[1]); f4 v = {lo.x, lo.y, hi.x, hi.y}; *(f4*)&h_lds[(e >> 2) * 16 + (e & 3) * 4] = v; } \
            pk.u = rr2; { int e = 1024 + tid; float2 lo = __half22float2(pk.h2[0]); float2 hi = __half22float2(pk.h2[1]); f4 v = {lo.x, lo.y, hi.x, hi.y}; *(f4*)&h_lds[(e >> 2) * 16 + (e & 3) * 4] = v; } \
            pk.u = rr3; { int e = 1536 + tid; float2 lo = __half22float2(pk.h2[0]); float2 hi = __half22float2(pk.h2[1]); f4 v = {lo.x, lo.y, hi.x, hi.y}; *(f4*)&h_lds[(e >> 2) * 16 + (e & 3) * 4] = v; } \
            pk.u = rr4; { int e = 2048 + tid; float2 lo = __half22float2(pk.h2[0]); float2 hi = __half22float2(pk.h2[1]); f4 v = {lo.x, lo.y, hi.x, hi.y}; *(f4*)&h_lds[(e >> 2) * 16 + (e & 3) * 4] = v; } \
        }                                                                                           \
        __syncthreads();                                                                            \
    }

__global__ void __launch_bounds__(512, 1) k_gru(const __half* __restrict__ xp,
                                                const float* __restrict__ Whh,
                                                const float* __restrict__ bhh,
                                                const float* __restrict__ fcw,
                                                u64* __restrict__ hgu,
                                                float* __restrict__ fcpart,
                                                unsigned* __restrict__ bar) {
    __shared__ __align__(16) float w_lds[640 * 16];   // [k][jj*4+g], g<3  (40960 B)
    __shared__ __align__(16) float h_lds[640 * 16];   // [k][16 cohort batches] (40960 B)
    __shared__ float red[8 * 16 * 12];                // 6144 B
    __shared__ float fcred[64];

    const int tid = threadIdx.x;
    const int blk = blockIdx.x;
    const int j0 = blk * 4;
    const int ksx = tid >> 4;            // 0..31
    const int jj = (tid >> 2) & 3;
    const int bg = tid & 3;
    const int lane = tid & 63;
    const int wid = tid >> 6;            // 0..7
    const int ej = tid >> 4;             // epilogue j-local (valid tid<64)
    const int eb = tid & 15;             // epilogue cohort batch

    // Load the block's 12 W_hh rows into LDS once (shared by both cohorts)
    for (int r = 0; r < 12; ++r) {
        int wjj = r / 3, wg = r % 3;
        const float* src = Whh + (size_t)(wg * 640 + j0 + wjj) * 640;
        for (int k = tid; k < 640; k += 512) w_lds[k * 16 + wjj * 4 + wg] = src[k];
    }
    float bh_r = 0.f, bh_z = 0.f, bh_n = 0.f, fw = 0.f, holdA = 0.f, holdB = 0.f;
    if (tid < 64) {
        int fj = j0 + ej;
        bh_r = bhh[fj];
        bh_z = bhh[640 + fj];
        bh_n = bhh[1280 + fj];
        fw = fcw[fj];
    }
    // pre-stage h_A(-1) = 0
    for (int i = tid; i < 640 * 16; i += 512) h_lds[i] = 0.f;

    // preload xp for t=0, both cohorts
    float xrA = 0.f, xzA = 0.f, xnA = 0.f, xrB = 0.f, xzB = 0.f, xnB = 0.f;
    if (tid < 64) {
        int j = j0 + ej;
        const __half* pA = xp + (size_t)eb * 1920;
        const __half* pB = xp + (size_t)(16 + eb) * 1920;
        xrA = __half2float(pA[j]); xzA = __half2float(pA[640 + j]); xnA = __half2float(pA[1280 + j]);
        xrB = __half2float(pB[j]); xzB = __half2float(pB[640 + j]); xnB = __half2float(pB[1280 + j]);
    }
    unsigned* barA = bar;
    unsigned* barB = bar + 256;          // byte offset 1024
    __syncthreads();

    for (int t = 0; t < 1000; ++t) {
        // half A(t): consume h_A(t-1) (already in h_lds), produce h_A(t),
        // tail: poll barB[t-1] (target 160*t, skip t=0), stage h_B(t-1) from B[t&1]
        GRU_HALF(xrA, xzA, xnA, holdA,
                 hgu + (size_t)(2 + (t & 1)) * 2560, barB, 160u * (unsigned)t,
                 hgu + (size_t)((t + 1) & 1) * 2560, barA, 0, 0)
        // half B(t): consume h_B(t-1), produce h_B(t),
        // tail: poll barA[t] (target 160*(t+1)), stage h_A(t) from A[(t+1)&1]
        GRU_HALF(xrB, xzB, xnB, holdB,
                 hgu + (size_t)((t + 1) & 1) * 2560, barA, 160u * (unsigned)(t + 1),
                 hgu + (size_t)(2 + ((t + 1) & 1)) * 2560, barB, 16, 16)
    }
}

// ---------------------------------------------------------------------------
// K9: final fc reduction: out[b*1000+t] = fc_b + sum_blk fcpart[blk][t][b]
__global__ void k_fc(const float* __restrict__ fcpart, const float* __restrict__ fcb,
                     float* __restrict__ out) {
    int gid = blockIdx.x * 256 + threadIdx.x;  // < 32000
    int t = gid >> 5;
    int b = gid & 31;
    float s = fcb[0];
    for (int blk = 0; blk < 160; ++blk) s += fcpart[(size_t)blk * 32000 + t * 32 + b];
    out[(size_t)b * 1000 + t] = s;
}

// ---------------------------------------------------------------------------
extern "C" void kernel_launch(void* const* d_in, const int* in_sizes, int n_in,
                              void* d_out, int out_size, void* d_ws, size_t ws_size,
                              hipStream_t stream) {
    const float* x      = (const float*)d_in[0];
    const float* a_vals = (const float*)d_in[1];
    const float* w_vals = (const float*)d_in[2];
    const float* dcls_w = (const float*)d_in[3];
    const float* dcls_p = (const float*)d_in[4];
    const float* dcls_b = (const float*)d_in[5];
    const float* gamma  = (const float*)d_in[6];
    const float* beta   = (const float*)d_in[7];
    const float* W_ih   = (const float*)d_in[8];
    const float* W_hh   = (const float*)d_in[9];
    const float* b_ih   = (const float*)d_in[10];
    const float* b_hh   = (const float*)d_in[11];
    const float* fc_w   = (const float*)d_in[12];
    const float* fc_b   = (const float*)d_in[13];
    char* w = (char*)d_ws;

    // ws layout (bytes). Peak total: ~164.0 MB.
    //   [0, 122,880,000)           xpH   fp16 32000x1920  -- phase D
    //       overlay [0, 81,920,000)        ybcgt fp32     -- phases A-B (dead before GEMM)
    //   [122,880,000, 163,840,000) seqH  fp16 32000x640   -- phases B-C
    //       overlay: hp fp32 + dk fp32  -- phase A;  fcpart fp32 -- phase D
    //   [163,840,000, 163,921,920) hgu   u64 [A0|A1|B0|B1] x 2560 (packed fp16 x4)
    //   [164,003,840, 164,004,352) bnsum fp32 128
    //   [164,004,352, 164,004,864) bnp   fp32 128
    //   [164,004,864, 164,006,912) bar   u32 16x32 (128B-spaced monotone counters, A then B)
    __half* xpH    = (__half*)(w);
    float* ybcgt   = (float*)(w);
    __half* seqH   = (__half*)(w + 122880000);
    float* hp      = (float*)(w + 122880000);
    float* dk      = (float*)(w + 122880000 + 4352000);
    float* fcpart  = (float*)(w + 122880000);
    u64* hgu       = (u64*)(w + 163840000);
    float* bnsum   = (float*)(w + 164003840);
    unsigned* bar  = (unsigned*)(w + 164004864);

    // zero h0 buffers + bn accumulators + bnp + barrier counters (tail spans all)
    hipMemsetAsync(w + 163840000, 0, 166912, stream);

    k_dk<<<dim3(315), dim3(256), 0, stream>>>(dcls_w, dcls_p, dk);
    k_ema<<<dim3(1088), dim3(256), 0, stream>>>(x, a_vals, w_vals, hp);
    k_conv<<<dim3(4, 10, 32), dim3(256), 0, stream>>>(hp, dk, dcls_b, ybcgt);
    k_bnstat<<<dim3(640), dim3(256), 0, stream>>>(ybcgt, bnsum);
    k_bnfin<<<dim3(1), dim3(64), 0, stream>>>(bnsum, gamma, beta, (float*)(w + 164004352));
    k_tr<<<dim3(16, 10, 32), dim3(256), 0, stream>>>(ybcgt, (float*)(w + 164004352), seqH);
    k_gemm<<<dim3(15, 250), dim3(256), 0, stream>>>(seqH, W_ih, b_ih, xpH);

    {
        const __half* xp_a = xpH;
        void* args[] = {(void*)&xp_a, (void*)&W_hh, (void*)&b_hh, (void*)&fc_w,
                        (void*)&hgu, (void*)&fcpart, (void*)&bar};
        hipLaunchCooperativeKernel((void*)k_gru, dim3(160), dim3(512), args, 0, stream);
    }

    k_fc<<<dim3(125), dim3(256), 0, stream>>>(fcpart, fc_b, (float*)d_out);
}

// Round 3
// 6972.809 us; speedup vs baseline: 1.1467x; 1.1467x over previous
//
#include <hip/hip_runtime.h>
#include <hip/hip_fp16.h>
#include <cstdint>

typedef float f4 __attribute__((ext_vector_type(4)));
typedef unsigned long long u64;

// Problem constants
// B=32, F=34, T=1000, K=7, S=3, F_DOWN=10, C=64, H=640, 3H=1920, T_MAX=9, PAD=4, MS_KS=200

// ---------------------------------------------------------------------------
// K1: build DCLS kernel dk[h][i][tau], h<640, i<14, tau<9
__global__ void k_dk(const float* __restrict__ dcls_w, const float* __restrict__ dcls_p,
                     float* __restrict__ dk) {
    int idx = blockIdx.x * 256 + threadIdx.x;
    if (idx >= 640 * 126) return;
    int h = idx / 126;
    int r = idx % 126;
    int i = r / 9;
    int tau = r % 9;
    float p = dcls_p[h * 14 + i];
    p = fminf(fmaxf(p, 0.f), 8.f);
    float tri = fmaxf(1.f - fabsf((float)tau - p), 0.f);
    dk[idx] = dcls_w[h * 14 + i] * tri;
}

// ---------------------------------------------------------------------------
// K2: EMA lowpass (200-tap truncated, exact) + highpass. hp[b][f][t]
__global__ void k_ema(const float* __restrict__ x, const float* __restrict__ a_vals,
                      const float* __restrict__ w_vals, float* __restrict__ hp) {
    __shared__ float xr[1024];
    int bf = blockIdx.x;               // b*34+f
    int f = bf % 34;
    int tid = threadIdx.x;
    const float* xs = x + (size_t)bf * 1000;
    for (int i = tid; i < 1000; i += 256) xr[i] = xs[i];
    for (int i = 1000 + tid; i < 1024; i += 256) xr[i] = 0.f;
    __syncthreads();
    float a = a_vals[f], wv = w_vals[f];
    float om = 1.f - a;
    int t1 = tid, t2 = tid + 256, t3 = tid + 512, t4 = tid + 768;
    bool v4 = (t4 < 1000);
    float a0 = 0.f, a1 = 0.f, a2 = 0.f, a3 = 0.f;
    float coef = a;
    for (int k = 0; k < 200; ++k) {
        a0 += (k <= t1 ? xr[t1 - k] : 0.f) * coef;
        a1 += xr[t2 - k] * coef;
        a2 += xr[t3 - k] * coef;
        a3 += (v4 ? xr[t4 - k] : 0.f) * coef;
        coef *= om;
    }
    float* op = hp + (size_t)bf * 1000;
    op[t1] = xr[t1] - wv * a0;
    op[t2] = xr[t2] - wv * a1;
    op[t3] = xr[t3] - wv * a2;
    if (v4) op[t4] = xr[t4] - wv * a3;
}

// ---------------------------------------------------------------------------
// K3: DCLS grouped conv. ybcgt[b][h=c*10+g][t] = bias[g*64+c] + sum_{i,tau} u * dk
__global__ void __launch_bounds__(256) k_conv(const float* __restrict__ hp,
                                              const float* __restrict__ dk,
                                              const float* __restrict__ dcls_b,
                                              float* __restrict__ ybcgt) {
    __shared__ float u[2 * 7 * 264];    // [pm][kk][264]
    __shared__ float dks[64 * 126];
    int tid = threadIdx.x;
    int t0 = blockIdx.x * 256;
    int g = blockIdx.y;
    int b = blockIdx.z;
    for (int idx = tid; idx < 8064; idx += 256) dks[idx] = dk[g * 8064 + idx];
    for (int idx = tid; idx < 3696; idx += 256) {
        int pm = idx / 1848;
        int rem = idx % 1848;
        int kk = rem / 264;
        int tt = rem % 264;
        int tg = t0 - 4 + tt;
        float v = (tg >= 0 && tg < 1000) ? hp[((size_t)(b * 34 + g * 3 + kk)) * 1000 + tg] : 0.f;
        u[idx] = pm ? fmaxf(-v, 0.f) : fmaxf(v, 0.f);
    }
    __syncthreads();
    int tl = tid & 63;
    int cg4 = tid >> 6;     // 0..3, c = cg4*16+ci
    float acc[16][4];
#pragma unroll
    for (int ci = 0; ci < 16; ++ci)
#pragma unroll
        for (int tq = 0; tq < 4; ++tq) acc[ci][tq] = 0.f;

    for (int i = 0; i < 14; ++i) {
#pragma unroll
        for (int tau = 0; tau < 9; ++tau) {
            const float* ub = u + i * 264 + tl + tau;
            float u0 = ub[0];
            float u1 = ub[64];
            float u2 = ub[128];
            float u3 = ub[192];
            const float* dp = dks + cg4 * 16 * 126 + i * 9 + tau;
#pragma unroll
            for (int ci = 0; ci < 16; ++ci) {
                float dv = dp[ci * 126];
                acc[ci][0] += u0 * dv;
                acc[ci][1] += u1 * dv;
                acc[ci][2] += u2 * dv;
                acc[ci][3] += u3 * dv;
            }
        }
    }
#pragma unroll
    for (int ci = 0; ci < 16; ++ci) {
        int c = cg4 * 16 + ci;
        float bias = dcls_b[g * 64 + c];
        size_t base = ((size_t)(b * 640 + c * 10 + g)) * 1000;
#pragma unroll
        for (int tq = 0; tq < 4; ++tq) {
            int t = t0 + tq * 64 + tl;
            if (t < 1000) ybcgt[base + t] = acc[ci][tq] + bias;
        }
    }
}

// ---------------------------------------------------------------------------
// K4: BN stats: per channel c sum & sumsq over (b,g,t). bnsum[0..63]=sum, [64..127]=sumsq
__global__ void k_bnstat(const float* __restrict__ ybcgt, float* __restrict__ bnsum) {
    int c = blockIdx.x / 10;
    int g = blockIdx.x % 10;
    int tid = threadIdx.x;
    float s = 0.f, q = 0.f;
    const float* base = ybcgt + ((size_t)(c * 10 + g)) * 1000;
    for (int b = 0; b < 32; ++b) {
        const float* p = base + (size_t)b * 640000;
        for (int t = tid; t < 1000; t += 256) {
            float v = p[t];
            s += v;
            q += v * v;
        }
    }
    for (int off = 1; off < 64; off <<= 1) {
        s += __shfl_xor(s, off);
        q += __shfl_xor(q, off);
    }
    __shared__ float rs[4], rq[4];
    if ((tid & 63) == 0) { rs[tid >> 6] = s; rq[tid >> 6] = q; }
    __syncthreads();
    if (tid == 0) {
        s = rs[0] + rs[1] + rs[2] + rs[3];
        q = rq[0] + rq[1] + rq[2] + rq[3];
        atomicAdd(&bnsum[c], s);
        atomicAdd(&bnsum[64 + c], q);
    }
}

// K5: BN finalize -> bnp[c]=scale, bnp[64+c]=shift
__global__ void k_bnfin(const float* __restrict__ bnsum, const float* __restrict__ gamma,
                        const float* __restrict__ beta, float* __restrict__ bnp) {
    int c = threadIdx.x;
    const float inv_n = 1.f / 320000.f;
    float mean = bnsum[c] * inv_n;
    float var = bnsum[64 + c] * inv_n - mean * mean;
    float sc = gamma[c] * rsqrtf(var + 1e-5f);
    bnp[c] = sc;
    bnp[64 + c] = beta[c] - mean * sc;
}

// ---------------------------------------------------------------------------
// K6: fused transpose + BN + sigmoid: seq[(t*32+b)*640 + h] = sigmoid(scale*y + shift) (fp16)
__global__ void k_tr(const float* __restrict__ ybcgt, const float* __restrict__ bnp,
                     __half* __restrict__ seq) {
    __shared__ float tile[64 * 65];
    int tid = threadIdx.x;
    int tt0 = blockIdx.x * 64;
    int h0 = blockIdx.y * 64;
    int b = blockIdx.z;
    int tx = tid & 63;
    int ty = tid >> 6;
#pragma unroll
    for (int r = 0; r < 16; ++r) {
        int hh = r * 4 + ty;
        int t = tt0 + tx;
        float v = (t < 1000) ? ybcgt[((size_t)(b * 640 + h0 + hh)) * 1000 + t] : 0.f;
        int c = (h0 + hh) / 10;
        float sarg = bnp[c] * v + bnp[64 + c];
        tile[hh * 65 + tx] = 1.f / (1.f + __expf(-sarg));
    }
    __syncthreads();
#pragma unroll
    for (int r = 0; r < 16; ++r) {
        int t = tt0 + r * 4 + ty;
        if (t < 1000)
            seq[((size_t)t * 32 + b) * 640 + h0 + tx] = __float2half(tile[tx * 65 + r * 4 + ty]);
    }
}

// ---------------------------------------------------------------------------
// K7: x_proj GEMM (unchanged, passing): BM=BN=128, BK=8, 256 thr, 8x8 micro,
// 16 NAMED f4 accs; __launch_bounds__(256,4); Bs swizzled to break bank alias.
#define BCOL(c) ((c) + (((c) >> 5) << 2))
__global__ void __launch_bounds__(256, 4) k_gemm(const __half* __restrict__ A,
                                                 const float* __restrict__ W,
                                                 const float* __restrict__ bih,
                                                 __half* __restrict__ C) {
    __shared__ float As[8][128];
    __shared__ float Bs[8][140];
    int tid = threadIdx.x;
    int n0 = blockIdx.x * 128;
    int m0 = blockIdx.y * 128;
    int tx = tid & 15;          // n-subtile: cols n0 + tx*8 .. +7
    int ty = tid >> 4;          // m-subtile: rows m0 + ty*8 .. +7
    int lm = tid >> 1;
    int lk4 = (tid & 1) * 4;
    int lmB = BCOL(lm);
    const int bc0 = BCOL(tx * 8);
    const int bc1 = BCOL(tx * 8 + 4);
    const __half* Ab = A + (size_t)(m0 + lm) * 640 + lk4;
    const float* Bb = W + (size_t)(n0 + lm) * 640 + lk4;

    f4 c0a = {0,0,0,0}, c0b = {0,0,0,0}, c1a = {0,0,0,0}, c1b = {0,0,0,0};
    f4 c2a = {0,0,0,0}, c2b = {0,0,0,0}, c3a = {0,0,0,0}, c3b = {0,0,0,0};
    f4 c4a = {0,0,0,0}, c4b = {0,0,0,0}, c5a = {0,0,0,0}, c5b = {0,0,0,0};
    f4 c6a = {0,0,0,0}, c6b = {0,0,0,0}, c7a = {0,0,0,0}, c7b = {0,0,0,0};

    for (int kt = 0; kt < 80; ++kt) {
        float2 araw = *(const float2*)(Ab + (size_t)kt * 8);   // 4 halves
        const __half2* ah = (const __half2*)&araw;
        float2 a01 = __half22float2(ah[0]);
        float2 a23 = __half22float2(ah[1]);
        float4 bv = *(const float4*)(Bb + (size_t)kt * 8);
        __syncthreads();
        As[lk4 + 0][lm] = a01.x; As[lk4 + 1][lm] = a01.y;
        As[lk4 + 2][lm] = a23.x; As[lk4 + 3][lm] = a23.y;
        Bs[lk4 + 0][lmB] = bv.x; Bs[lk4 + 1][lmB] = bv.y;
        Bs[lk4 + 2][lmB] = bv.z; Bs[lk4 + 3][lmB] = bv.w;
        __syncthreads();
#pragma unroll
        for (int kk = 0; kk < 8; ++kk) {
            f4 blo = *(const f4*)&Bs[kk][bc0];
            f4 bhi = *(const f4*)&Bs[kk][bc1];
            f4 alo = *(const f4*)&As[kk][ty * 8];
            f4 ahi = *(const f4*)&As[kk][ty * 8 + 4];
            c0a += alo.x * blo; c0b += alo.x * bhi;
            c1a += alo.y * blo; c1b += alo.y * bhi;
            c2a += alo.z * blo; c2b += alo.z * bhi;
            c3a += alo.w * blo; c3b += alo.w * bhi;
            c4a += ahi.x * blo; c4b += ahi.x * bhi;
            c5a += ahi.y * blo; c5b += ahi.y * bhi;
            c6a += ahi.z * blo; c6b += ahi.z * bhi;
            c7a += ahi.w * blo; c7b += ahi.w * bhi;
        }
    }
    f4 bblo = *(const f4*)&bih[n0 + tx * 8];
    f4 bbhi = *(const f4*)&bih[n0 + tx * 8 + 4];
    union { __half h[8]; float4 v; } ob;
#define STORE_ROW(i, ra, rb)                                                     \
    {                                                                            \
        f4 lo = ra + bblo; f4 hi = rb + bbhi;                                    \
        ob.h[0] = __float2half(lo.x); ob.h[1] = __float2half(lo.y);              \
        ob.h[2] = __float2half(lo.z); ob.h[3] = __float2half(lo.w);              \
        ob.h[4] = __float2half(hi.x); ob.h[5] = __float2half(hi.y);              \
        ob.h[6] = __float2half(hi.z); ob.h[7] = __float2half(hi.w);              \
        *(float4*)&C[(size_t)(m0 + ty * 8 + i) * 1920 + n0 + tx * 8] = ob.v;     \
    }
    STORE_ROW(0, c0a, c0b) STORE_ROW(1, c1a, c1b) STORE_ROW(2, c2a, c2b)
    STORE_ROW(3, c3a, c3b) STORE_ROW(4, c4a, c4b) STORE_ROW(5, c5a, c5b)
    STORE_ROW(6, c6a, c6b) STORE_ROW(7, c7a, c7b)
#undef STORE_ROW
}

// ---------------------------------------------------------------------------
// K8 v3: persistent GRU, v1 structure + EPOCH-FUSED h exchange (no grid barrier).
// Each h pair is published as u64 = {2 x fp16 data, 32-bit epoch tag}. Consumers
// spin on the data loads themselves (upper32 == t) -- the readiness signal IS
// the data, deleting: s_waitcnt drain, fetch_add arrival, counter poll, and the
// post-poll data round-trip. Safety with 2 buffers (no arrival counters):
// a block writing tag t+2 into buf[t&1] must first have SEEN all tag-(t+1)
// stores; each tag-(t+1) store is issued after __syncthreads (per-thread vmcnt
// drain), i.e. after ALL that block's epoch-t reads returned. Returned reads
// can't be corrupted retroactively -> no lost data, no deadlock (covers cold-
// start skew: a block can't overwrite buf0 with tag 2 until every block stored
// tag 1, which happens after their buf0 reads).
// hgu layout: 2 buffers x 10240 u64; entry e = j*16 + bpair, bpair=b/2.
// h(t) stored with tag (t+1) into buf[(t+1)&1]; step t stages from buf[t&1]
// expecting tag t (zero-init buffers give h(-1)=0 with tag 0).
// fc: per-wave shfl_xor(32) partial (2 j-rows) -> 320 partial rows, no LDS.
__global__ void __launch_bounds__(512, 1) k_gru(const __half* __restrict__ xp,
                                                const float* __restrict__ Whh,
                                                const float* __restrict__ bhh,
                                                const float* __restrict__ fcw,
                                                u64* __restrict__ hgu,
                                                float* __restrict__ fcpart,
                                                unsigned* __restrict__ bar) {
    __shared__ __align__(16) float w_lds[640 * 16];   // [k][jj*4+g], g<3  (40960 B)
    __shared__ __align__(16) float h_lds[640 * 32];   // full h staging    (81920 B)
    float* red = h_lds;            // overlay after compute: [8][16][24] = 3072 floats

    const int tid = threadIdx.x;
    const int blk = blockIdx.x;
    const int j0 = blk * 4;
    const int ksx = tid >> 4;            // 0..31
    const int jj = (tid >> 2) & 3;
    const int bg = tid & 3;
    const int lane = tid & 63;
    const int wid = tid >> 6;            // 0..7

    // Load the block's 12 W_hh rows into LDS once (persists across all steps)
    for (int r = 0; r < 12; ++r) {
        int wjj = r / 3, wg = r % 3;
        const float* src = Whh + (size_t)(wg * 640 + j0 + wjj) * 640;
        for (int k = tid; k < 640; k += 512) w_lds[k * 16 + wjj * 4 + wg] = src[k];
    }
    float bh_r = 0.f, bh_z = 0.f, bh_n = 0.f, fw = 0.f, hold = 0.f;
    if (tid < 128) {
        int fj = j0 + (tid >> 5);
        bh_r = bhh[fj];
        bh_z = bhh[640 + fj];
        bh_n = bhh[1280 + fj];
        fw = fcw[fj];
    }
    __syncthreads();

    // preload xp for t=0 (plain cached loads)
    float xr = 0.f, xz = 0.f, xn = 0.f;
    if (tid < 128) {
        const __half* xpt = xp + (size_t)(tid & 31) * 1920;
        int j = j0 + (tid >> 5);
        xr = __half2float(xpt[j]);
        xz = __half2float(xpt[640 + j]);
        xn = __half2float(xpt[1280 + j]);
    }

    for (int t = 0; t < 1000; ++t) {
        const u64* hcur = hgu + (size_t)(t & 1) * 10240;
        u64* hnxt = hgu + (size_t)((t + 1) & 1) * 10240;

        // ---- epoch-spun staging: 20 tagged u64 loads (2 fp16 + tag each) ----
        u64 rr[20];
#pragma unroll
        for (int i = 0; i < 20; ++i)
            rr[i] = __hip_atomic_load(&hcur[i * 512 + tid],
                                      __ATOMIC_RELAXED, __HIP_MEMORY_SCOPE_AGENT);
        {
            const unsigned tg = (unsigned)t;
            for (;;) {
                int nbad = 0;
#pragma unroll
                for (int i = 0; i < 20; ++i)
                    if ((unsigned)(rr[i] >> 32) != tg) {
                        rr[i] = __hip_atomic_load(&hcur[i * 512 + tid],
                                                  __ATOMIC_RELAXED, __HIP_MEMORY_SCOPE_AGENT);
                        ++nbad;
                    }
                if (nbad == 0) break;
                __builtin_amdgcn_s_sleep(1);
            }
        }
#pragma unroll
        for (int i = 0; i < 20; ++i) {
            int e = i * 512 + tid;                   // e = k*16 + bpair
            union { unsigned u; __half2 h2; } pk;
            pk.u = (unsigned)rr[i];
            float2 fl = __half22float2(pk.h2);
            *(float2*)&h_lds[(e >> 4) * 32 + (e & 15) * 2] = fl;
        }
        __syncthreads();

        // prefetch xp for step t+1 (overlaps with compute below)
        float nxr = 0.f, nxz = 0.f, nxn = 0.f;
        if (t + 1 < 1000 && tid < 128) {
            const __half* xpt = xp + (size_t)(t + 1) * 61440 + (size_t)(tid & 31) * 1920;
            int j = j0 + (tid >> 5);
            nxr = __half2float(xpt[j]);
            nxz = __half2float(xpt[640 + j]);
            nxn = __half2float(xpt[1280 + j]);
        }

        float a0[8], a1[8], a2[8];
#pragma unroll
        for (int i = 0; i < 8; ++i) { a0[i] = 0.f; a1[i] = 0.f; a2[i] = 0.f; }

#pragma unroll 4
        for (int ii = 0; ii < 20; ++ii) {
            int k = ii * 32 + ksx;
            float4 wv = *(const float4*)(w_lds + k * 16 + jj * 4);
            float4 h0 = *(const float4*)(h_lds + k * 32 + bg * 8);
            float4 h1 = *(const float4*)(h_lds + k * 32 + bg * 8 + 4);
            a0[0] += wv.x * h0.x; a0[1] += wv.x * h0.y; a0[2] += wv.x * h0.z; a0[3] += wv.x * h0.w;
            a0[4] += wv.x * h1.x; a0[5] += wv.x * h1.y; a0[6] += wv.x * h1.z; a0[7] += wv.x * h1.w;
            a1[0] += wv.y * h0.x; a1[1] += wv.y * h0.y; a1[2] += wv.y * h0.z; a1[3] += wv.y * h0.w;
            a1[4] += wv.y * h1.x; a1[5] += wv.y * h1.y; a1[6] += wv.y * h1.z; a1[7] += wv.y * h1.w;
            a2[0] += wv.z * h0.x; a2[1] += wv.z * h0.y; a2[2] += wv.z * h0.z; a2[3] += wv.z * h0.w;
            a2[4] += wv.z * h1.x; a2[5] += wv.z * h1.y; a2[6] += wv.z * h1.z; a2[7] += wv.z * h1.w;
        }
        // reduce over the wave's 4 ksx values (lane distance 16, 32)
#pragma unroll
        for (int i = 0; i < 8; ++i) {
            a0[i] += __shfl_xor(a0[i], 16); a0[i] += __shfl_xor(a0[i], 32);
            a1[i] += __shfl_xor(a1[i], 16); a1[i] += __shfl_xor(a1[i], 32);
            a2[i] += __shfl_xor(a2[i], 16); a2[i] += __shfl_xor(a2[i], 32);
        }
        __syncthreads();   // h_lds reads done; safe to reuse as 'red'
        if (lane < 16) {
            float* rp = red + (wid * 16 + lane) * 24;
#pragma unroll
            for (int i = 0; i < 8; ++i) { rp[i] = a0[i]; rp[8 + i] = a1[i]; rp[16 + i] = a2[i]; }
        }
        __syncthreads();
        if (tid < 128) {
            int fb = tid & 31;
            int rr_ = ((tid >> 5) << 2) | (fb >> 3);
            int bif = fb & 7;
            float hr = bh_r, hz = bh_z, hn = bh_n;
#pragma unroll
            for (int w2 = 0; w2 < 8; ++w2) {
                const float* rp = red + (w2 * 16 + rr_) * 24;
                hr += rp[bif];
                hz += rp[8 + bif];
                hn += rp[16 + bif];
            }
            int j = j0 + (tid >> 5);
            float r_ = 1.f / (1.f + __expf(-(xr + hr)));
            float z_ = 1.f / (1.f + __expf(-(xz + hz)));
            float pre = xn + r_ * hn;
            float e2 = __expf(-2.f * fabsf(pre));
            float tn = (1.f - e2) / (1.f + e2);
            float n_ = (pre >= 0.f) ? tn : -tn;
            float hnew = (1.f - z_) * n_ + z_ * hold;
            hold = hnew;
            // publish {2 x fp16, epoch t+1}: even-b lanes store one u64
            float h1v = __shfl_xor(hnew, 1);
            __half2 v2 = __floats2half2_rn(hnew, h1v);   // valid on even-fb lanes
            union { __half2 h2; unsigned u; } cv;
            cv.h2 = v2;
            if ((fb & 1) == 0)
                __hip_atomic_store(&hnxt[(size_t)j * 16 + (fb >> 1)],
                                   (u64)cv.u | ((u64)(unsigned)(t + 1) << 32),
                                   __ATOMIC_RELAXED, __HIP_MEMORY_SCOPE_AGENT);
            // fc partial: sum this wave's 2 j-rows, store per-wave row (no LDS)
            float fv = hnew * fw;
            fv += __shfl_xor(fv, 32);
            if (lane < 32)
                fcpart[(size_t)(blk * 2 + wid) * 32000 + t * 32 + fb] = fv;
        }
        xr = nxr; xz = nxz; xn = nxn;
        __syncthreads();   // epilogue's red reads done before next staging overwrites h_lds
    }
}

// ---------------------------------------------------------------------------
// K9: final fc reduction: out[b*1000+t] = fc_b + sum over 320 partial rows
__global__ void k_fc(const float* __restrict__ fcpart, const float* __restrict__ fcb,
                     float* __restrict__ out) {
    int gid = blockIdx.x * 256 + threadIdx.x;  // < 32000
    int t = gid >> 5;
    int b = gid & 31;
    float s = fcb[0];
    for (int blk = 0; blk < 320; ++blk) s += fcpart[(size_t)blk * 32000 + t * 32 + b];
    out[(size_t)b * 1000 + t] = s;
}

// ---------------------------------------------------------------------------
extern "C" void kernel_launch(void* const* d_in, const int* in_sizes, int n_in,
                              void* d_out, int out_size, void* d_ws, size_t ws_size,
                              hipStream_t stream) {
    const float* x      = (const float*)d_in[0];
    const float* a_vals = (const float*)d_in[1];
    const float* w_vals = (const float*)d_in[2];
    const float* dcls_w = (const float*)d_in[3];
    const float* dcls_p = (const float*)d_in[4];
    const float* dcls_b = (const float*)d_in[5];
    const float* gamma  = (const float*)d_in[6];
    const float* beta   = (const float*)d_in[7];
    const float* W_ih   = (const float*)d_in[8];
    const float* W_hh   = (const float*)d_in[9];
    const float* b_ih   = (const float*)d_in[10];
    const float* b_hh   = (const float*)d_in[11];
    const float* fc_w   = (const float*)d_in[12];
    const float* fc_b   = (const float*)d_in[13];
    char* w = (char*)d_ws;

    // ws layout (bytes). Peak total: ~164.0 MB.
    //   [0, 122,880,000)           xpH   fp16 32000x1920  -- phase D
    //       overlay [0, 81,920,000)        ybcgt fp32     -- phases A-B (dead before GEMM)
    //   [122,880,000, 163,840,000) seqH  fp16 32000x640   -- phases B-C
    //       overlay: hp fp32 + dk fp32  -- phase A;  fcpart fp32 320x32000 -- phase D
    //   [163,840,000, 164,003,840) hgu   u64 2x10240 (epoch-tagged h pairs)
    //   [164,003,840, 164,004,352) bnsum fp32 128
    //   [164,004,352, 164,004,864) bnp   fp32 128
    //   [164,004,864, 164,006,912) bar   u32 (legacy, unused)
    __half* xpH    = (__half*)(w);
    float* ybcgt   = (float*)(w);
    __half* seqH   = (__half*)(w + 122880000);
    float* hp      = (float*)(w + 122880000);
    float* dk      = (float*)(w + 122880000 + 4352000);
    float* fcpart  = (float*)(w + 122880000);
    u64* hgu       = (u64*)(w + 163840000);
    float* bnsum   = (float*)(w + 164003840);
    unsigned* bar  = (unsigned*)(w + 164004864);

    // zero h0 epoch-tagged buffers (tag 0 = h(-1)) + bn accumulators + bnp + bar
    hipMemsetAsync(w + 163840000, 0, 166912, stream);

    k_dk<<<dim3(315), dim3(256), 0, stream>>>(dcls_w, dcls_p, dk);
    k_ema<<<dim3(1088), dim3(256), 0, stream>>>(x, a_vals, w_vals, hp);
    k_conv<<<dim3(4, 10, 32), dim3(256), 0, stream>>>(hp, dk, dcls_b, ybcgt);
    k_bnstat<<<dim3(640), dim3(256), 0, stream>>>(ybcgt, bnsum);
    k_bnfin<<<dim3(1), dim3(64), 0, stream>>>(bnsum, gamma, beta, (float*)(w + 164004352));
    k_tr<<<dim3(16, 10, 32), dim3(256), 0, stream>>>(ybcgt, (float*)(w + 164004352), seqH);
    k_gemm<<<dim3(15, 250), dim3(256), 0, stream>>>(seqH, W_ih, b_ih, xpH);

    {
        const __half* xp_a = xpH;
        void* args[] = {(void*)&xp_a, (void*)&W_hh, (void*)&b_hh, (void*)&fc_w,
                        (void*)&hgu, (void*)&fcpart, (void*)&bar};
        hipLaunchCooperativeKernel((void*)k_gru, dim3(160), dim3(512), args, 0, stream);
    }

    k_fc<<<dim3(125), dim3(256), 0, stream>>>(fcpart, fc_b, (float*)d_out);
}

// Round 5
// 6000.159 us; speedup vs baseline: 1.3326x; 1.1621x over previous
//
#include <hip/hip_runtime.h>
#include <hip/hip_fp16.h>
#include <cstdint>

typedef float f4 __attribute__((ext_vector_type(4)));
typedef _Float16 h2v __attribute__((ext_vector_type(2)));
typedef unsigned long long u64;

__device__ __forceinline__ float dot2f(h2v a, h2v b, float c) {
#if __has_builtin(__builtin_amdgcn_fdot2)
    return __builtin_amdgcn_fdot2(a, b, c, false);
#else
    return c + (float)a.x * (float)b.x + (float)a.y * (float)b.y;
#endif
}

// Problem constants
// B=32, F=34, T=1000, K=7, S=3, F_DOWN=10, C=64, H=640, 3H=1920, T_MAX=9, PAD=4, MS_KS=200

// ---------------------------------------------------------------------------
// K1: build DCLS kernel dk[h][i][tau], h<640, i<14, tau<9
__global__ void k_dk(const float* __restrict__ dcls_w, const float* __restrict__ dcls_p,
                     float* __restrict__ dk) {
    int idx = blockIdx.x * 256 + threadIdx.x;
    if (idx >= 640 * 126) return;
    int h = idx / 126;
    int r = idx % 126;
    int i = r / 9;
    int tau = r % 9;
    float p = dcls_p[h * 14 + i];
    p = fminf(fmaxf(p, 0.f), 8.f);
    float tri = fmaxf(1.f - fabsf((float)tau - p), 0.f);
    dk[idx] = dcls_w[h * 14 + i] * tri;
}

// ---------------------------------------------------------------------------
// K2: EMA lowpass (200-tap truncated, exact) + highpass. hp[b][f][t]
__global__ void k_ema(const float* __restrict__ x, const float* __restrict__ a_vals,
                      const float* __restrict__ w_vals, float* __restrict__ hp) {
    __shared__ float xr[1024];
    int bf = blockIdx.x;               // b*34+f
    int f = bf % 34;
    int tid = threadIdx.x;
    const float* xs = x + (size_t)bf * 1000;
    for (int i = tid; i < 1000; i += 256) xr[i] = xs[i];
    for (int i = 1000 + tid; i < 1024; i += 256) xr[i] = 0.f;
    __syncthreads();
    float a = a_vals[f], wv = w_vals[f];
    float om = 1.f - a;
    int t1 = tid, t2 = tid + 256, t3 = tid + 512, t4 = tid + 768;
    bool v4 = (t4 < 1000);
    float a0 = 0.f, a1 = 0.f, a2 = 0.f, a3 = 0.f;
    float coef = a;
    for (int k = 0; k < 200; ++k) {
        a0 += (k <= t1 ? xr[t1 - k] : 0.f) * coef;
        a1 += xr[t2 - k] * coef;
        a2 += xr[t3 - k] * coef;
        a3 += (v4 ? xr[t4 - k] : 0.f) * coef;
        coef *= om;
    }
    float* op = hp + (size_t)bf * 1000;
    op[t1] = xr[t1] - wv * a0;
    op[t2] = xr[t2] - wv * a1;
    op[t3] = xr[t3] - wv * a2;
    if (v4) op[t4] = xr[t4] - wv * a3;
}

// ---------------------------------------------------------------------------
// K3: DCLS grouped conv. ybcgt[b][h=c*10+g][t] = bias[g*64+c] + sum_{i,tau} u * dk
__global__ void __launch_bounds__(256) k_conv(const float* __restrict__ hp,
                                              const float* __restrict__ dk,
                                              const float* __restrict__ dcls_b,
                                              float* __restrict__ ybcgt) {
    __shared__ float u[2 * 7 * 264];    // [pm][kk][264]
    __shared__ float dks[64 * 126];
    int tid = threadIdx.x;
    int t0 = blockIdx.x * 256;
    int g = blockIdx.y;
    int b = blockIdx.z;
    for (int idx = tid; idx < 8064; idx += 256) dks[idx] = dk[g * 8064 + idx];
    for (int idx = tid; idx < 3696; idx += 256) {
        int pm = idx / 1848;
        int rem = idx % 1848;
        int kk = rem / 264;
        int tt = rem % 264;
        int tg = t0 - 4 + tt;
        float v = (tg >= 0 && tg < 1000) ? hp[((size_t)(b * 34 + g * 3 + kk)) * 1000 + tg] : 0.f;
        u[idx] = pm ? fmaxf(-v, 0.f) : fmaxf(v, 0.f);
    }
    __syncthreads();
    int tl = tid & 63;
    int cg4 = tid >> 6;     // 0..3, c = cg4*16+ci
    float acc[16][4];
#pragma unroll
    for (int ci = 0; ci < 16; ++ci)
#pragma unroll
        for (int tq = 0; tq < 4; ++tq) acc[ci][tq] = 0.f;

    for (int i = 0; i < 14; ++i) {
#pragma unroll
        for (int tau = 0; tau < 9; ++tau) {
            const float* ub = u + i * 264 + tl + tau;
            float u0 = ub[0];
            float u1 = ub[64];
            float u2 = ub[128];
            float u3 = ub[192];
            const float* dp = dks + cg4 * 16 * 126 + i * 9 + tau;
#pragma unroll
            for (int ci = 0; ci < 16; ++ci) {
                float dv = dp[ci * 126];
                acc[ci][0] += u0 * dv;
                acc[ci][1] += u1 * dv;
                acc[ci][2] += u2 * dv;
                acc[ci][3] += u3 * dv;
            }
        }
    }
#pragma unroll
    for (int ci = 0; ci < 16; ++ci) {
        int c = cg4 * 16 + ci;
        float bias = dcls_b[g * 64 + c];
        size_t base = ((size_t)(b * 640 + c * 10 + g)) * 1000;
#pragma unroll
        for (int tq = 0; tq < 4; ++tq) {
            int t = t0 + tq * 64 + tl;
            if (t < 1000) ybcgt[base + t] = acc[ci][tq] + bias;
        }
    }
}

// ---------------------------------------------------------------------------
// K4: BN stats: per channel c sum & sumsq over (b,g,t). bnsum[0..63]=sum, [64..127]=sumsq
__global__ void k_bnstat(const float* __restrict__ ybcgt, float* __restrict__ bnsum) {
    int c = blockIdx.x / 10;
    int g = blockIdx.x % 10;
    int tid = threadIdx.x;
    float s = 0.f, q = 0.f;
    const float* base = ybcgt + ((size_t)(c * 10 + g)) * 1000;
    for (int b = 0; b < 32; ++b) {
        const float* p = base + (size_t)b * 640000;
        for (int t = tid; t < 1000; t += 256) {
            float v = p[t];
            s += v;
            q += v * v;
        }
    }
    for (int off = 1; off < 64; off <<= 1) {
        s += __shfl_xor(s, off);
        q += __shfl_xor(q, off);
    }
    __shared__ float rs[4], rq[4];
    if ((tid & 63) == 0) { rs[tid >> 6] = s; rq[tid >> 6] = q; }
    __syncthreads();
    if (tid == 0) {
        s = rs[0] + rs[1] + rs[2] + rs[3];
        q = rq[0] + rq[1] + rq[2] + rq[3];
        atomicAdd(&bnsum[c], s);
        atomicAdd(&bnsum[64 + c], q);
    }
}

// K5: BN finalize -> bnp[c]=scale, bnp[64+c]=shift
__global__ void k_bnfin(const float* __restrict__ bnsum, const float* __restrict__ gamma,
                        const float* __restrict__ beta, float* __restrict__ bnp) {
    int c = threadIdx.x;
    const float inv_n = 1.f / 320000.f;
    float mean = bnsum[c] * inv_n;
    float var = bnsum[64 + c] * inv_n - mean * mean;
    float sc = gamma[c] * rsqrtf(var + 1e-5f);
    bnp[c] = sc;
    bnp[64 + c] = beta[c] - mean * sc;
}

// ---------------------------------------------------------------------------
// K6: fused transpose + BN + sigmoid: seq[(t*32+b)*640 + h] = sigmoid(scale*y + shift) (fp16)
__global__ void k_tr(const float* __restrict__ ybcgt, const float* __restrict__ bnp,
                     __half* __restrict__ seq) {
    __shared__ float tile[64 * 65];
    int tid = threadIdx.x;
    int tt0 = blockIdx.x * 64;
    int h0 = blockIdx.y * 64;
    int b = blockIdx.z;
    int tx = tid & 63;
    int ty = tid >> 6;
#pragma unroll
    for (int r = 0; r < 16; ++r) {
        int hh = r * 4 + ty;
        int t = tt0 + tx;
        float v = (t < 1000) ? ybcgt[((size_t)(b * 640 + h0 + hh)) * 1000 + t] : 0.f;
        int c = (h0 + hh) / 10;
        float sarg = bnp[c] * v + bnp[64 + c];
        tile[hh * 65 + tx] = 1.f / (1.f + __expf(-sarg));
    }
    __syncthreads();
#pragma unroll
    for (int r = 0; r < 16; ++r) {
        int t = tt0 + r * 4 + ty;
        if (t < 1000)
            seq[((size_t)t * 32 + b) * 640 + h0 + tx] = __float2half(tile[tx * 65 + r * 4 + ty]);
    }
}

// ---------------------------------------------------------------------------
// K7: x_proj GEMM (unchanged, passing)
#define BCOL(c) ((c) + (((c) >> 5) << 2))
__global__ void __launch_bounds__(256, 4) k_gemm(const __half* __restrict__ A,
                                                 const float* __restrict__ W,
                                                 const float* __restrict__ bih,
                                                 __half* __restrict__ C) {
    __shared__ float As[8][128];
    __shared__ float Bs[8][140];
    int tid = threadIdx.x;
    int n0 = blockIdx.x * 128;
    int m0 = blockIdx.y * 128;
    int tx = tid & 15;
    int ty = tid >> 4;
    int lm = tid >> 1;
    int lk4 = (tid & 1) * 4;
    int lmB = BCOL(lm);
    const int bc0 = BCOL(tx * 8);
    const int bc1 = BCOL(tx * 8 + 4);
    const __half* Ab = A + (size_t)(m0 + lm) * 640 + lk4;
    const float* Bb = W + (size_t)(n0 + lm) * 640 + lk4;

    f4 c0a = {0,0,0,0}, c0b = {0,0,0,0}, c1a = {0,0,0,0}, c1b = {0,0,0,0};
    f4 c2a = {0,0,0,0}, c2b = {0,0,0,0}, c3a = {0,0,0,0}, c3b = {0,0,0,0};
    f4 c4a = {0,0,0,0}, c4b = {0,0,0,0}, c5a = {0,0,0,0}, c5b = {0,0,0,0};
    f4 c6a = {0,0,0,0}, c6b = {0,0,0,0}, c7a = {0,0,0,0}, c7b = {0,0,0,0};

    for (int kt = 0; kt < 80; ++kt) {
        float2 araw = *(const float2*)(Ab + (size_t)kt * 8);
        const __half2* ah = (const __half2*)&araw;
        float2 a01 = __half22float2(ah[0]);
        float2 a23 = __half22float2(ah[1]);
        float4 bv = *(const float4*)(Bb + (size_t)kt * 8);
        __syncthreads();
        As[lk4 + 0][lm] = a01.x; As[lk4 + 1][lm] = a01.y;
        As[lk4 + 2][lm] = a23.x; As[lk4 + 3][lm] = a23.y;
        Bs[lk4 + 0][lmB] = bv.x; Bs[lk4 + 1][lmB] = bv.y;
        Bs[lk4 + 2][lmB] = bv.z; Bs[lk4 + 3][lmB] = bv.w;
        __syncthreads();
#pragma unroll
        for (int kk = 0; kk < 8; ++kk) {
            f4 blo = *(const f4*)&Bs[kk][bc0];
            f4 bhi = *(const f4*)&Bs[kk][bc1];
            f4 alo = *(const f4*)&As[kk][ty * 8];
            f4 ahi = *(const f4*)&As[kk][ty * 8 + 4];
            c0a += alo.x * blo; c0b += alo.x * bhi;
            c1a += alo.y * blo; c1b += alo.y * bhi;
            c2a += alo.z * blo; c2b += alo.z * bhi;
            c3a += alo.w * blo; c3b += alo.w * bhi;
            c4a += ahi.x * blo; c4b += ahi.x * bhi;
            c5a += ahi.y * blo; c5b += ahi.y * bhi;
            c6a += ahi.z * blo; c6b += ahi.z * bhi;
            c7a += ahi.w * blo; c7b += ahi.w * bhi;
        }
    }
    f4 bblo = *(const f4*)&bih[n0 + tx * 8];
    f4 bbhi = *(const f4*)&bih[n0 + tx * 8 + 4];
    union { __half h[8]; float4 v; } ob;
#define STORE_ROW(i, ra, rb)                                                     \
    {                                                                            \
        f4 lo = ra + bblo; f4 hi = rb + bbhi;                                    \
        ob.h[0] = __float2half(lo.x); ob.h[1] = __float2half(lo.y);              \
        ob.h[2] = __float2half(lo.z); ob.h[3] = __float2half(lo.w);              \
        ob.h[4] = __float2half(hi.x); ob.h[5] = __float2half(hi.y);              \
        ob.h[6] = __float2half(hi.z); ob.h[7] = __float2half(hi.w);              \
        *(float4*)&C[(size_t)(m0 + ty * 8 + i) * 1920 + n0 + tx * 8] = ob.v;     \
    }
    STORE_ROW(0, c0a, c0b) STORE_ROW(1, c1a, c1b) STORE_ROW(2, c2a, c2b)
    STORE_ROW(3, c3a, c3b) STORE_ROW(4, c4a, c4b) STORE_ROW(5, c5a, c5b)
    STORE_ROW(6, c6a, c6b) STORE_ROW(7, c7a, c7b)
#undef STORE_ROW
}

// ---------------------------------------------------------------------------
// K8 v4: persistent GRU. v3's epoch-fused exchange (unchanged protocol) +
// LDS-throughput attack:
//  * W_hh and h in LDS as fp16; contraction via v_dot2_f32_f16 over k-pairs
//    (fp16 products are exact in fp32 accum; only W/h quantization error).
//  * exchange payload repacked as k-pairs {h[2kp],h[2kp+1]} per batch, so
//    staging writes the received half2 straight to LDS (b32, no conversion).
//  * NO shuffle reduction: every thread writes its 24 partials (6 x b128) to
//    red[ksx*4+jj][100]; the 2-wave epilogue sums the 32 ksx columns directly.
// Thread map: ksx=tid>>4 (32 k-slices, 10 kpair iters), jj=(tid>>2)&3 (j row),
// bg=tid&3 (8 batches). acc[3 gates][8 batches] per thread.
// DS per thread/step: 20 b32 stage + 30 b128 matvec + 6 b128 red (+96 b32
// epilogue on 2 waves) ~= 2.3us/CU vs v3's ~4.5us.
__global__ void __launch_bounds__(512, 1) k_gru(const __half* __restrict__ xp,
                                                const float* __restrict__ Whh,
                                                const float* __restrict__ bhh,
                                                const float* __restrict__ fcw,
                                                u64* __restrict__ hgu,
                                                float* __restrict__ fcpart,
                                                unsigned* __restrict__ bar) {
    __shared__ __align__(16) h2v w_ldsH[320 * 16];   // [kp][jj][slot g<3+pad]  20KB
    __shared__ __align__(16) h2v h_ldsH[320 * 36];   // [kp][b(32)+pad4]        46KB
    __shared__ __align__(16) float red[128 * 100];   // [ksx*4+jj][g*32+b +pad] 51.2KB

    const int tid = threadIdx.x;
    const int blk = blockIdx.x;
    const int j0 = blk * 4;
    const int ksx = tid >> 4;            // 0..31
    const int jj = (tid >> 2) & 3;       // j row 0..3
    const int bg = tid & 3;              // batch group (8 each)
    const int wid = tid >> 6;

    // ---- one-time: W_hh rows (3 gates x 4 j) -> fp16 k-pair LDS ----
    for (int idx = tid; idx < 5120; idx += 512) {
        int slot = idx & 3;              // g or pad
        int wjj = (idx >> 2) & 3;
        int kp = idx >> 4;
        h2v v = {(_Float16)0.f, (_Float16)0.f};
        if (slot < 3) {
            const float2 wv2 = *(const float2*)&Whh[(size_t)(slot * 640 + j0 + wjj) * 640 + 2 * kp];
            v.x = (_Float16)wv2.x;
            v.y = (_Float16)wv2.y;
        }
        w_ldsH[idx] = v;
    }
    float bh_r = 0.f, bh_z = 0.f, bh_n = 0.f, fw = 0.f, hold = 0.f;
    if (tid < 128) {
        int fj = j0 + (tid >> 5);
        bh_r = bhh[fj];
        bh_z = bhh[640 + fj];
        bh_n = bhh[1280 + fj];
        fw = fcw[fj];
    }
    __syncthreads();

    // preload xp for t=0
    float xr = 0.f, xz = 0.f, xn = 0.f;
    if (tid < 128) {
        const __half* xpt = xp + (size_t)(tid & 31) * 1920;
        int j = j0 + (tid >> 5);
        xr = __half2float(xpt[j]);
        xz = __half2float(xpt[640 + j]);
        xn = __half2float(xpt[1280 + j]);
    }

    for (int t = 0; t < 1000; ++t) {
        const u64* hcur = hgu + (size_t)(t & 1) * 10240;
        u64* hnxt = hgu + (size_t)((t + 1) & 1) * 10240;

        // ---- epoch-spun staging: 20 tagged u64 loads {half2 kpair, tag} ----
        u64 rr[20];
#pragma unroll
        for (int i = 0; i < 20; ++i)
            rr[i] = __hip_atomic_load(&hcur[i * 512 + tid],
                                      __ATOMIC_RELAXED, __HIP_MEMORY_SCOPE_AGENT);
        {
            const unsigned tg = (unsigned)t;
            for (;;) {
                int nbad = 0;
#pragma unroll
                for (int i = 0; i < 20; ++i)
                    if ((unsigned)(rr[i] >> 32) != tg) {
                        rr[i] = __hip_atomic_load(&hcur[i * 512 + tid],
                                                  __ATOMIC_RELAXED, __HIP_MEMORY_SCOPE_AGENT);
                        ++nbad;
                    }
                if (nbad == 0) break;
                __builtin_amdgcn_s_sleep(1);
            }
        }
#pragma unroll
        for (int i = 0; i < 20; ++i) {
            int e = i * 512 + tid;                   // e = kp*32 + b
            union { unsigned u; h2v h2; } pk;
            pk.u = (unsigned)rr[i];
            h_ldsH[(e >> 5) * 36 + (e & 31)] = pk.h2;   // b32 write, no conversion
        }
        __syncthreads();

        // prefetch xp for t+1 (overlaps compute)
        float nxr = 0.f, nxz = 0.f, nxn = 0.f;
        if (t + 1 < 1000 && tid < 128) {
            const __half* xpt = xp + (size_t)(t + 1) * 61440 + (size_t)(tid & 31) * 1920;
            int j = j0 + (tid >> 5);
            nxr = __half2float(xpt[j]);
            nxz = __half2float(xpt[640 + j]);
            nxn = __half2float(xpt[1280 + j]);
        }

        float a0[8], a1[8], a2[8];
#pragma unroll
        for (int i = 0; i < 8; ++i) { a0[i] = 0.f; a1[i] = 0.f; a2[i] = 0.f; }

#pragma unroll
        for (int ii = 0; ii < 10; ++ii) {
            int kp = ii * 32 + ksx;
            f4 wq = *(const f4*)&w_ldsH[kp * 16 + jj * 4];
            f4 hq0 = *(const f4*)&h_ldsH[kp * 36 + bg * 8];
            f4 hq1 = *(const f4*)&h_ldsH[kp * 36 + bg * 8 + 4];
            const h2v* wp = (const h2v*)&wq;
            const h2v* hp0 = (const h2v*)&hq0;
            const h2v* hp1 = (const h2v*)&hq1;
#pragma unroll
            for (int bi = 0; bi < 4; ++bi) {
                a0[bi] = dot2f(wp[0], hp0[bi], a0[bi]);
                a1[bi] = dot2f(wp[1], hp0[bi], a1[bi]);
                a2[bi] = dot2f(wp[2], hp0[bi], a2[bi]);
                a0[4 + bi] = dot2f(wp[0], hp1[bi], a0[4 + bi]);
                a1[4 + bi] = dot2f(wp[1], hp1[bi], a1[4 + bi]);
                a2[4 + bi] = dot2f(wp[2], hp1[bi], a2[4 + bi]);
            }
        }
        // ---- direct partial dump (no shuffles): red[ksx*4+jj][g*32 + bg*8 ..] ----
        {
            float* rp = red + (ksx * 4 + jj) * 100 + bg * 8;
            *(f4*)&rp[0]   = (f4){a0[0], a0[1], a0[2], a0[3]};
            *(f4*)&rp[4]   = (f4){a0[4], a0[5], a0[6], a0[7]};
            *(f4*)&rp[32]  = (f4){a1[0], a1[1], a1[2], a1[3]};
            *(f4*)&rp[36]  = (f4){a1[4], a1[5], a1[6], a1[7]};
            *(f4*)&rp[64]  = (f4){a2[0], a2[1], a2[2], a2[3]};
            *(f4*)&rp[68]  = (f4){a2[4], a2[5], a2[6], a2[7]};
        }
        __syncthreads();
        if (tid < 128) {
            int b = tid & 31;
            int jl = tid >> 5;
            float hr = bh_r, hz = bh_z, hn = bh_n;
#pragma unroll
            for (int k2 = 0; k2 < 32; ++k2) {
                const float* rp = red + (k2 * 4 + jl) * 100 + b;
                hr += rp[0];
                hz += rp[32];
                hn += rp[64];
            }
            int j = j0 + jl;
            float r_ = 1.f / (1.f + __expf(-(xr + hr)));
            float z_ = 1.f / (1.f + __expf(-(xz + hz)));
            float pre = xn + r_ * hn;
            float e2 = __expf(-2.f * fabsf(pre));
            float tn = (1.f - e2) / (1.f + e2);
            float n_ = (pre >= 0.f) ? tn : -tn;
            float hnew = (1.f - z_) * n_ + z_ * hold;
            hold = hnew;
            // publish k-pair {h[even j], h[odd j]} + epoch tag (even-jl lanes store)
            float hpart = __shfl_xor(hnew, 32);
            if ((jl & 1) == 0) {
                union { h2v h2; unsigned u; } cv;
                cv.h2.x = (_Float16)hnew;
                cv.h2.y = (_Float16)hpart;
                int kp = blk * 2 + (jl >> 1);
                __hip_atomic_store(&hnxt[(size_t)kp * 32 + b],
                                   (u64)cv.u | ((u64)(unsigned)(t + 1) << 32),
                                   __ATOMIC_RELAXED, __HIP_MEMORY_SCOPE_AGENT);
            }
            // fc partial: per-wave sum of its 2 j-rows (no LDS)
            float fv = hnew * fw;
            fv += __shfl_xor(fv, 32);
            if ((tid & 63) < 32)
                fcpart[(size_t)(blk * 2 + wid) * 32000 + t * 32 + b] = fv;
        }
        xr = nxr; xz = nxz; xn = nxn;
        __syncthreads();   // red reads done before next step's red writes
    }
}

// ---------------------------------------------------------------------------
// K9: final fc reduction: out[b*1000+t] = fc_b + sum over 320 partial rows
__global__ void k_fc(const float* __restrict__ fcpart, const float* __restrict__ fcb,
                     float* __restrict__ out) {
    int gid = blockIdx.x * 256 + threadIdx.x;  // < 32000
    int t = gid >> 5;
    int b = gid & 31;
    float s = fcb[0];
    for (int blk = 0; blk < 320; ++blk) s += fcpart[(size_t)blk * 32000 + t * 32 + b];
    out[(size_t)b * 1000 + t] = s;
}

// ---------------------------------------------------------------------------
extern "C" void kernel_launch(void* const* d_in, const int* in_sizes, int n_in,
                              void* d_out, int out_size, void* d_ws, size_t ws_size,
                              hipStream_t stream) {
    const float* x      = (const float*)d_in[0];
    const float* a_vals = (const float*)d_in[1];
    const float* w_vals = (const float*)d_in[2];
    const float* dcls_w = (const float*)d_in[3];
    const float* dcls_p = (const float*)d_in[4];
    const float* dcls_b = (const float*)d_in[5];
    const float* gamma  = (const float*)d_in[6];
    const float* beta   = (const float*)d_in[7];
    const float* W_ih   = (const float*)d_in[8];
    const float* W_hh   = (const float*)d_in[9];
    const float* b_ih   = (const float*)d_in[10];
    const float* b_hh   = (const float*)d_in[11];
    const float* fc_w   = (const float*)d_in[12];
    const float* fc_b   = (const float*)d_in[13];
    char* w = (char*)d_ws;

    // ws layout (bytes). Peak total: ~164.0 MB.
    //   [0, 122,880,000)           xpH   fp16 32000x1920  -- phase D
    //       overlay [0, 81,920,000)        ybcgt fp32     -- phases A-B (dead before GEMM)
    //   [122,880,000, 163,840,000) seqH  fp16 32000x640   -- phases B-C
    //       overlay: hp fp32 + dk fp32  -- phase A;  fcpart fp32 320x32000 -- phase D
    //   [163,840,000, 164,003,840) hgu   u64 2x10240 (epoch-tagged h k-pairs)
    //   [164,003,840, 164,004,352) bnsum fp32 128
    //   [164,004,352, 164,004,864) bnp   fp32 128
    //   [164,004,864, 164,006,912) bar   u32 (legacy, unused)
    __half* xpH    = (__half*)(w);
    float* ybcgt   = (float*)(w);
    __half* seqH   = (__half*)(w + 122880000);
    float* hp      = (float*)(w + 122880000);
    float* dk      = (float*)(w + 122880000 + 4352000);
    float* fcpart  = (float*)(w + 122880000);
    u64* hgu       = (u64*)(w + 163840000);
    float* bnsum   = (float*)(w + 164003840);
    unsigned* bar  = (unsigned*)(w + 164004864);

    // zero h0 epoch-tagged buffers (tag 0 = h(-1)) + bn accumulators + bnp + bar
    hipMemsetAsync(w + 163840000, 0, 166912, stream);

    k_dk<<<dim3(315), dim3(256), 0, stream>>>(dcls_w, dcls_p, dk);
    k_ema<<<dim3(1088), dim3(256), 0, stream>>>(x, a_vals, w_vals, hp);
    k_conv<<<dim3(4, 10, 32), dim3(256), 0, stream>>>(hp, dk, dcls_b, ybcgt);
    k_bnstat<<<dim3(640), dim3(256), 0, stream>>>(ybcgt, bnsum);
    k_bnfin<<<dim3(1), dim3(64), 0, stream>>>(bnsum, gamma, beta, (float*)(w + 164004352));
    k_tr<<<dim3(16, 10, 32), dim3(256), 0, stream>>>(ybcgt, (float*)(w + 164004352), seqH);
    k_gemm<<<dim3(15, 250), dim3(256), 0, stream>>>(seqH, W_ih, b_ih, xpH);

    {
        const __half* xp_a = xpH;
        void* args[] = {(void*)&xp_a, (void*)&W_hh, (void*)&b_hh, (void*)&fc_w,
                        (void*)&hgu, (void*)&fcpart, (void*)&bar};
        hipLaunchCooperativeKernel((void*)k_gru, dim3(160), dim3(512), args, 0, stream);
    }

    k_fc<<<dim3(125), dim3(256), 0, stream>>>(fcpart, fc_b, (float*)d_out);
}

// Round 6
// 5078.878 us; speedup vs baseline: 1.5743x; 1.1814x over previous
//
#include <hip/hip_runtime.h>
#include <hip/hip_fp16.h>
#include <cstdint>

typedef float f4 __attribute__((ext_vector_type(4)));
typedef _Float16 h2v __attribute__((ext_vector_type(2)));
typedef _Float16 half8 __attribute__((ext_vector_type(8)));
typedef unsigned u32x4 __attribute__((ext_vector_type(4)));
typedef unsigned long long u64;

// Problem constants
// B=32, F=34, T=1000, K=7, S=3, F_DOWN=10, C=64, H=640, 3H=1920, T_MAX=9, PAD=4, MS_KS=200

// ---------------------------------------------------------------------------
// K1: build DCLS kernel dk[h][i][tau], h<640, i<14, tau<9
__global__ void k_dk(const float* __restrict__ dcls_w, const float* __restrict__ dcls_p,
                     float* __restrict__ dk) {
    int idx = blockIdx.x * 256 + threadIdx.x;
    if (idx >= 640 * 126) return;
    int h = idx / 126;
    int r = idx % 126;
    int i = r / 9;
    int tau = r % 9;
    float p = dcls_p[h * 14 + i];
    p = fminf(fmaxf(p, 0.f), 8.f);
    float tri = fmaxf(1.f - fabsf((float)tau - p), 0.f);
    dk[idx] = dcls_w[h * 14 + i] * tri;
}

// ---------------------------------------------------------------------------
// K2: EMA lowpass (200-tap truncated, exact) + highpass. hp[b][f][t]
__global__ void k_ema(const float* __restrict__ x, const float* __restrict__ a_vals,
                      const float* __restrict__ w_vals, float* __restrict__ hp) {
    __shared__ float xr[1024];
    int bf = blockIdx.x;               // b*34+f
    int f = bf % 34;
    int tid = threadIdx.x;
    const float* xs = x + (size_t)bf * 1000;
    for (int i = tid; i < 1000; i += 256) xr[i] = xs[i];
    for (int i = 1000 + tid; i < 1024; i += 256) xr[i] = 0.f;
    __syncthreads();
    float a = a_vals[f], wv = w_vals[f];
    float om = 1.f - a;
    int t1 = tid, t2 = tid + 256, t3 = tid + 512, t4 = tid + 768;
    bool v4 = (t4 < 1000);
    float a0 = 0.f, a1 = 0.f, a2 = 0.f, a3 = 0.f;
    float coef = a;
    for (int k = 0; k < 200; ++k) {
        a0 += (k <= t1 ? xr[t1 - k] : 0.f) * coef;
        a1 += xr[t2 - k] * coef;
        a2 += xr[t3 - k] * coef;
        a3 += (v4 ? xr[t4 - k] : 0.f) * coef;
        coef *= om;
    }
    float* op = hp + (size_t)bf * 1000;
    op[t1] = xr[t1] - wv * a0;
    op[t2] = xr[t2] - wv * a1;
    op[t3] = xr[t3] - wv * a2;
    if (v4) op[t4] = xr[t4] - wv * a3;
}

// ---------------------------------------------------------------------------
// K3: DCLS grouped conv. ybcgt[b][h=c*10+g][t] = bias[g*64+c] + sum_{i,tau} u * dk
__global__ void __launch_bounds__(256) k_conv(const float* __restrict__ hp,
                                              const float* __restrict__ dk,
                                              const float* __restrict__ dcls_b,
                                              float* __restrict__ ybcgt) {
    __shared__ float u[2 * 7 * 264];    // [pm][kk][264]
    __shared__ float dks[64 * 126];
    int tid = threadIdx.x;
    int t0 = blockIdx.x * 256;
    int g = blockIdx.y;
    int b = blockIdx.z;
    for (int idx = tid; idx < 8064; idx += 256) dks[idx] = dk[g * 8064 + idx];
    for (int idx = tid; idx < 3696; idx += 256) {
        int pm = idx / 1848;
        int rem = idx % 1848;
        int kk = rem / 264;
        int tt = rem % 264;
        int tg = t0 - 4 + tt;
        float v = (tg >= 0 && tg < 1000) ? hp[((size_t)(b * 34 + g * 3 + kk)) * 1000 + tg] : 0.f;
        u[idx] = pm ? fmaxf(-v, 0.f) : fmaxf(v, 0.f);
    }
    __syncthreads();
    int tl = tid & 63;
    int cg4 = tid >> 6;     // 0..3, c = cg4*16+ci
    float acc[16][4];
#pragma unroll
    for (int ci = 0; ci < 16; ++ci)
#pragma unroll
        for (int tq = 0; tq < 4; ++tq) acc[ci][tq] = 0.f;

    for (int i = 0; i < 14; ++i) {
#pragma unroll
        for (int tau = 0; tau < 9; ++tau) {
            const float* ub = u + i * 264 + tl + tau;
            float u0 = ub[0];
            float u1 = ub[64];
            float u2 = ub[128];
            float u3 = ub[192];
            const float* dp = dks + cg4 * 16 * 126 + i * 9 + tau;
#pragma unroll
            for (int ci = 0; ci < 16; ++ci) {
                float dv = dp[ci * 126];
                acc[ci][0] += u0 * dv;
                acc[ci][1] += u1 * dv;
                acc[ci][2] += u2 * dv;
                acc[ci][3] += u3 * dv;
            }
        }
    }
#pragma unroll
    for (int ci = 0; ci < 16; ++ci) {
        int c = cg4 * 16 + ci;
        float bias = dcls_b[g * 64 + c];
        size_t base = ((size_t)(b * 640 + c * 10 + g)) * 1000;
#pragma unroll
        for (int tq = 0; tq < 4; ++tq) {
            int t = t0 + tq * 64 + tl;
            if (t < 1000) ybcgt[base + t] = acc[ci][tq] + bias;
        }
    }
}

// ---------------------------------------------------------------------------
// K4: BN stats: per channel c sum & sumsq over (b,g,t). bnsum[0..63]=sum, [64..127]=sumsq
__global__ void k_bnstat(const float* __restrict__ ybcgt, float* __restrict__ bnsum) {
    int c = blockIdx.x / 10;
    int g = blockIdx.x % 10;
    int tid = threadIdx.x;
    float s = 0.f, q = 0.f;
    const float* base = ybcgt + ((size_t)(c * 10 + g)) * 1000;
    for (int b = 0; b < 32; ++b) {
        const float* p = base + (size_t)b * 640000;
        for (int t = tid; t < 1000; t += 256) {
            float v = p[t];
            s += v;
            q += v * v;
        }
    }
    for (int off = 1; off < 64; off <<= 1) {
        s += __shfl_xor(s, off);
        q += __shfl_xor(q, off);
    }
    __shared__ float rs[4], rq[4];
    if ((tid & 63) == 0) { rs[tid >> 6] = s; rq[tid >> 6] = q; }
    __syncthreads();
    if (tid == 0) {
        s = rs[0] + rs[1] + rs[2] + rs[3];
        q = rq[0] + rq[1] + rq[2] + rq[3];
        atomicAdd(&bnsum[c], s);
        atomicAdd(&bnsum[64 + c], q);
    }
}

// K5: BN finalize -> bnp[c]=scale, bnp[64+c]=shift
__global__ void k_bnfin(const float* __restrict__ bnsum, const float* __restrict__ gamma,
                        const float* __restrict__ beta, float* __restrict__ bnp) {
    int c = threadIdx.x;
    const float inv_n = 1.f / 320000.f;
    float mean = bnsum[c] * inv_n;
    float var = bnsum[64 + c] * inv_n - mean * mean;
    float sc = gamma[c] * rsqrtf(var + 1e-5f);
    bnp[c] = sc;
    bnp[64 + c] = beta[c] - mean * sc;
}

// ---------------------------------------------------------------------------
// K6: fused transpose + BN + sigmoid: seq[(t*32+b)*640 + h] = sigmoid(scale*y + shift) (fp16)
__global__ void k_tr(const float* __restrict__ ybcgt, const float* __restrict__ bnp,
                     __half* __restrict__ seq) {
    __shared__ float tile[64 * 65];
    int tid = threadIdx.x;
    int tt0 = blockIdx.x * 64;
    int h0 = blockIdx.y * 64;
    int b = blockIdx.z;
    int tx = tid & 63;
    int ty = tid >> 6;
#pragma unroll
    for (int r = 0; r < 16; ++r) {
        int hh = r * 4 + ty;
        int t = tt0 + tx;
        float v = (t < 1000) ? ybcgt[((size_t)(b * 640 + h0 + hh)) * 1000 + t] : 0.f;
        int c = (h0 + hh) / 10;
        float sarg = bnp[c] * v + bnp[64 + c];
        tile[hh * 65 + tx] = 1.f / (1.f + __expf(-sarg));
    }
    __syncthreads();
#pragma unroll
    for (int r = 0; r < 16; ++r) {
        int t = tt0 + r * 4 + ty;
        if (t < 1000)
            seq[((size_t)t * 32 + b) * 640 + h0 + tx] = __float2half(tile[tx * 65 + r * 4 + ty]);
    }
}

// ---------------------------------------------------------------------------
// K7: x_proj GEMM (unchanged, passing)
#define BCOL(c) ((c) + (((c) >> 5) << 2))
__global__ void __launch_bounds__(256, 4) k_gemm(const __half* __restrict__ A,
                                                 const float* __restrict__ W,
                                                 const float* __restrict__ bih,
                                                 __half* __restrict__ C) {
    __shared__ float As[8][128];
    __shared__ float Bs[8][140];
    int tid = threadIdx.x;
    int n0 = blockIdx.x * 128;
    int m0 = blockIdx.y * 128;
    int tx = tid & 15;
    int ty = tid >> 4;
    int lm = tid >> 1;
    int lk4 = (tid & 1) * 4;
    int lmB = BCOL(lm);
    const int bc0 = BCOL(tx * 8);
    const int bc1 = BCOL(tx * 8 + 4);
    const __half* Ab = A + (size_t)(m0 + lm) * 640 + lk4;
    const float* Bb = W + (size_t)(n0 + lm) * 640 + lk4;

    f4 c0a = {0,0,0,0}, c0b = {0,0,0,0}, c1a = {0,0,0,0}, c1b = {0,0,0,0};
    f4 c2a = {0,0,0,0}, c2b = {0,0,0,0}, c3a = {0,0,0,0}, c3b = {0,0,0,0};
    f4 c4a = {0,0,0,0}, c4b = {0,0,0,0}, c5a = {0,0,0,0}, c5b = {0,0,0,0};
    f4 c6a = {0,0,0,0}, c6b = {0,0,0,0}, c7a = {0,0,0,0}, c7b = {0,0,0,0};

    for (int kt = 0; kt < 80; ++kt) {
        float2 araw = *(const float2*)(Ab + (size_t)kt * 8);
        const __half2* ah = (const __half2*)&araw;
        float2 a01 = __half22float2(ah[0]);
        float2 a23 = __half22float2(ah[1]);
        float4 bv = *(const float4*)(Bb + (size_t)kt * 8);
        __syncthreads();
        As[lk4 + 0][lm] = a01.x; As[lk4 + 1][lm] = a01.y;
        As[lk4 + 2][lm] = a23.x; As[lk4 + 3][lm] = a23.y;
        Bs[lk4 + 0][lmB] = bv.x; Bs[lk4 + 1][lmB] = bv.y;
        Bs[lk4 + 2][lmB] = bv.z; Bs[lk4 + 3][lmB] = bv.w;
        __syncthreads();
#pragma unroll
        for (int kk = 0; kk < 8; ++kk) {
            f4 blo = *(const f4*)&Bs[kk][bc0];
            f4 bhi = *(const f4*)&Bs[kk][bc1];
            f4 alo = *(const f4*)&As[kk][ty * 8];
            f4 ahi = *(const f4*)&As[kk][ty * 8 + 4];
            c0a += alo.x * blo; c0b += alo.x * bhi;
            c1a += alo.y * blo; c1b += alo.y * bhi;
            c2a += alo.z * blo; c2b += alo.z * bhi;
            c3a += alo.w * blo; c3b += alo.w * bhi;
            c4a += ahi.x * blo; c4b += ahi.x * bhi;
            c5a += ahi.y * blo; c5b += ahi.y * bhi;
            c6a += ahi.z * blo; c6b += ahi.z * bhi;
            c7a += ahi.w * blo; c7b += ahi.w * bhi;
        }
    }
    f4 bblo = *(const f4*)&bih[n0 + tx * 8];
    f4 bbhi = *(const f4*)&bih[n0 + tx * 8 + 4];
    union { __half h[8]; float4 v; } ob;
#define STORE_ROW(i, ra, rb)                                                     \
    {                                                                            \
        f4 lo = ra + bblo; f4 hi = rb + bbhi;                                    \
        ob.h[0] = __float2half(lo.x); ob.h[1] = __float2half(lo.y);              \
        ob.h[2] = __float2half(lo.z); ob.h[3] = __float2half(lo.w);              \
        ob.h[4] = __float2half(hi.x); ob.h[5] = __float2half(hi.y);              \
        ob.h[6] = __float2half(hi.z); ob.h[7] = __float2half(hi.w);              \
        *(float4*)&C[(size_t)(m0 + ty * 8 + i) * 1920 + n0 + tx * 8] = ob.v;     \
    }
    STORE_ROW(0, c0a, c0b) STORE_ROW(1, c1a, c1b) STORE_ROW(2, c2a, c2b)
    STORE_ROW(3, c3a, c3b) STORE_ROW(4, c4a, c4b) STORE_ROW(5, c5a, c5b)
    STORE_ROW(6, c6a, c6b) STORE_ROW(7, c7a, c7b)
#undef STORE_ROW
}

// ---------------------------------------------------------------------------
// K8 v5: MFMA persistent GRU. 40 blocks x 512 thr; block owns 16 j-rows
// (40x16=640, no padding). Per step: W(48x640) x h(640x32) via
// mfma_f32_16x16x32_f16: 6 waves each own one 16x16 tile (3 gates x 2
// batch-halves), 20 MFMA over K=640, W A-frags PERMANENT in registers
// (80 VGPR, loaded once from global). h staged in LDS [b][kp-pair] so each
// k-step's B-frag is one ds_read_b128. k-slot permutation cancels (A and B
// use the same slot->k map); C layout is the HW-verified col=lane&15,
// row=(lane>>4)*4+reg. Epilogue: fully parallel, 512 threads = one (j,b)
// each: 3 LDS reads + gates + publish. Exchange: v3/v4's epoch-tagged
// 2-buffer protocol, unchanged semantics (spin on data loads, tag==t).
__global__ void __launch_bounds__(512, 1) k_gru(const __half* __restrict__ xp,
                                                const float* __restrict__ Whh,
                                                const float* __restrict__ bhh,
                                                const float* __restrict__ fcw,
                                                u64* __restrict__ hgu,
                                                float* __restrict__ fcpart,
                                                unsigned* __restrict__ bar) {
    __shared__ __align__(16) h2v h_lds[32 * 324];     // [b][kp], stride 324 (41.5KB)
    __shared__ __align__(16) float red[3 * 32 * 20];  // [g][b][j], stride 20 (7.7KB)
    __shared__ float fcred[8 * 33];                   // [wave][b]

    const int tid = threadIdx.x;
    const int blk = blockIdx.x;
    const int j0 = blk * 16;
    const int lane = tid & 63;
    const int wid = tid >> 6;            // 0..7
    const int b_ep = tid & 31;           // epilogue batch
    const int j_ep = tid >> 5;           // epilogue j-local 0..15
    const int bq = tid & 31;             // staging batch
    const int kpg = tid >> 5;            // staging kp-group 0..15

    // ---- one-time: A-fragments (W rows, fp16) into registers, waves 0..5 ----
    // wave w: tile (g = w>>1, nh = w&1); lane: m = lane&15 (j row), kq = lane>>4.
    // afrag[s] elem i <-> k = s*32 + kq*8 + i.
    const int g = wid >> 1, nh = wid & 1;
    half8 afrag[20];
    if (wid < 6) {
        int m = lane & 15;
        int kq = lane >> 4;
        const float* wrow = Whh + (size_t)(g * 640 + j0 + m) * 640;
#pragma unroll
        for (int s = 0; s < 20; ++s) {
            float4 w0 = *(const float4*)&wrow[s * 32 + kq * 8];
            float4 w1 = *(const float4*)&wrow[s * 32 + kq * 8 + 4];
            afrag[s] = (half8){(_Float16)w0.x, (_Float16)w0.y, (_Float16)w0.z, (_Float16)w0.w,
                               (_Float16)w1.x, (_Float16)w1.y, (_Float16)w1.z, (_Float16)w1.w};
        }
    }
    float bh_r = bhh[j0 + j_ep];
    float bh_z = bhh[640 + j0 + j_ep];
    float bh_n = bhh[1280 + j0 + j_ep];
    float fw = fcw[j0 + j_ep];
    float hold = 0.f;

    // preload xp for t=0: thread (j_ep, b_ep)
    float xr, xz, xn;
    {
        const __half* xpt = xp + (size_t)b_ep * 1920;
        xr = __half2float(xpt[j0 + j_ep]);
        xz = __half2float(xpt[640 + j0 + j_ep]);
        xn = __half2float(xpt[1280 + j0 + j_ep]);
    }

    for (int t = 0; t < 1000; ++t) {
        const u64* hcur = hgu + (size_t)(t & 1) * 10240;
        u64* hnxt = hgu + (size_t)((t + 1) & 1) * 10240;

        // ---- epoch-spun staging: thread handles b=bq, kp = kpg*20 .. +19 ----
        u64 rr[20];
#pragma unroll
        for (int i = 0; i < 20; ++i)
            rr[i] = __hip_atomic_load(&hcur[(kpg * 20 + i) * 32 + bq],
                                      __ATOMIC_RELAXED, __HIP_MEMORY_SCOPE_AGENT);
        {
            const unsigned tg = (unsigned)t;
            for (;;) {
                int nbad = 0;
#pragma unroll
                for (int i = 0; i < 20; ++i)
                    if ((unsigned)(rr[i] >> 32) != tg) {
                        rr[i] = __hip_atomic_load(&hcur[(kpg * 20 + i) * 32 + bq],
                                                  __ATOMIC_RELAXED, __HIP_MEMORY_SCOPE_AGENT);
                        ++nbad;
                    }
                if (nbad == 0) break;
                __builtin_amdgcn_s_sleep(1);
            }
        }
        // 5 x b128 LDS writes (4 consecutive kp each)
#pragma unroll
        for (int c = 0; c < 5; ++c) {
            u32x4 v = {(unsigned)rr[c * 4], (unsigned)rr[c * 4 + 1],
                       (unsigned)rr[c * 4 + 2], (unsigned)rr[c * 4 + 3]};
            *(u32x4*)&h_lds[bq * 324 + kpg * 20 + c * 4] = v;
        }
        __syncthreads();   // S1: h staged

        // prefetch xp for t+1 (global loads overlap MFMA below)
        float nxr = 0.f, nxz = 0.f, nxn = 0.f;
        if (t + 1 < 1000) {
            const __half* xpt = xp + ((size_t)(t + 1) * 32 + b_ep) * 1920;
            nxr = __half2float(xpt[j0 + j_ep]);
            nxz = __half2float(xpt[640 + j0 + j_ep]);
            nxn = __half2float(xpt[1280 + j0 + j_ep]);
        }

        // ---- MFMA: 6 waves, 20 k-steps ----
        if (wid < 6) {
            int bb = nh * 16 + (lane & 15);
            int kq = lane >> 4;
            const h2v* hb = &h_lds[bb * 324 + kq * 4];
            f4 acc = {0.f, 0.f, 0.f, 0.f};
#pragma unroll
            for (int s = 0; s < 20; ++s) {
                half8 bfrag = *(const half8*)&hb[s * 16];
                acc = __builtin_amdgcn_mfma_f32_16x16x32_f16(afrag[s], bfrag, acc, 0, 0, 0);
            }
            // C: lane holds rows kq*4..+3 (j), col bb (batch)
            *(f4*)&red[(g * 32 + bb) * 20 + kq * 4] = acc;
        }
        __syncthreads();   // S2: red ready

        // ---- fully-parallel epilogue: thread = (j_ep, b_ep) ----
        {
            float hr = bh_r + red[(0 * 32 + b_ep) * 20 + j_ep];
            float hz = bh_z + red[(1 * 32 + b_ep) * 20 + j_ep];
            float hn = bh_n + red[(2 * 32 + b_ep) * 20 + j_ep];
            float r_ = 1.f / (1.f + __expf(-(xr + hr)));
            float z_ = 1.f / (1.f + __expf(-(xz + hz)));
            float pre = xn + r_ * hn;
            float e2 = __expf(-2.f * fabsf(pre));
            float tn = (1.f - e2) / (1.f + e2);
            float n_ = (pre >= 0.f) ? tn : -tn;
            float hnew = (1.f - z_) * n_ + z_ * hold;
            hold = hnew;
            // publish: j-pair (even j with odd j) packed fp16 + epoch tag.
            // wave covers j = 2*wid (lanes<32) and 2*wid+1 (lanes>=32).
            float hp_ = __shfl_xor(hnew, 32);
            if ((j_ep & 1) == 0) {
                union { h2v h2; unsigned u; } cv;
                cv.h2.x = (_Float16)hnew;
                cv.h2.y = (_Float16)hp_;
                __hip_atomic_store(&hnxt[(size_t)(blk * 8 + wid) * 32 + b_ep],
                                   (u64)cv.u | ((u64)(unsigned)(t + 1) << 32),
                                   __ATOMIC_RELAXED, __HIP_MEMORY_SCOPE_AGENT);
            }
            // fc partial: pair-sum within wave, then per-wave row to LDS
            float fv = hnew * fw;
            fv += __shfl_xor(fv, 32);
            if (lane < 32) fcred[wid * 33 + b_ep] = fv;
        }
        xr = nxr; xz = nxz; xn = nxn;
        __syncthreads();   // S3: red/fcred reads done; h_lds free for next stage
        if (tid < 32) {
            float s = 0.f;
#pragma unroll
            for (int w2 = 0; w2 < 8; ++w2) s += fcred[w2 * 33 + tid];
            __hip_atomic_store(&fcpart[(size_t)blk * 32000 + t * 32 + tid], s,
                               __ATOMIC_RELAXED, __HIP_MEMORY_SCOPE_AGENT);
        }
    }
}

// ---------------------------------------------------------------------------
// K9: final fc reduction: out[b*1000+t] = fc_b + sum over 40 partial rows
__global__ void k_fc(const float* __restrict__ fcpart, const float* __restrict__ fcb,
                     float* __restrict__ out) {
    int gid = blockIdx.x * 256 + threadIdx.x;  // < 32000
    int t = gid >> 5;
    int b = gid & 31;
    float s = fcb[0];
    for (int blk = 0; blk < 40; ++blk) s += fcpart[(size_t)blk * 32000 + t * 32 + b];
    out[(size_t)b * 1000 + t] = s;
}

// ---------------------------------------------------------------------------
extern "C" void kernel_launch(void* const* d_in, const int* in_sizes, int n_in,
                              void* d_out, int out_size, void* d_ws, size_t ws_size,
                              hipStream_t stream) {
    const float* x      = (const float*)d_in[0];
    const float* a_vals = (const float*)d_in[1];
    const float* w_vals = (const float*)d_in[2];
    const float* dcls_w = (const float*)d_in[3];
    const float* dcls_p = (const float*)d_in[4];
    const float* dcls_b = (const float*)d_in[5];
    const float* gamma  = (const float*)d_in[6];
    const float* beta   = (const float*)d_in[7];
    const float* W_ih   = (const float*)d_in[8];
    const float* W_hh   = (const float*)d_in[9];
    const float* b_ih   = (const float*)d_in[10];
    const float* b_hh   = (const float*)d_in[11];
    const float* fc_w   = (const float*)d_in[12];
    const float* fc_b   = (const float*)d_in[13];
    char* w = (char*)d_ws;

    // ws layout (bytes). Peak total: ~164.0 MB.
    //   [0, 122,880,000)           xpH   fp16 32000x1920  -- phase D
    //       overlay [0, 81,920,000)        ybcgt fp32     -- phases A-B (dead before GEMM)
    //   [122,880,000, 163,840,000) seqH  fp16 32000x640   -- phases B-C
    //       overlay: hp fp32 + dk fp32  -- phase A;  fcpart fp32 40x32000 -- phase D
    //   [163,840,000, 164,003,840) hgu   u64 2x10240 (epoch-tagged h k-pairs)
    //   [164,003,840, 164,004,352) bnsum fp32 128
    //   [164,004,352, 164,004,864) bnp   fp32 128
    //   [164,004,864, 164,006,912) bar   u32 (legacy, unused)
    __half* xpH    = (__half*)(w);
    float* ybcgt   = (float*)(w);
    __half* seqH   = (__half*)(w + 122880000);
    float* hp      = (float*)(w + 122880000);
    float* dk      = (float*)(w + 122880000 + 4352000);
    float* fcpart  = (float*)(w + 122880000);
    u64* hgu       = (u64*)(w + 163840000);
    float* bnsum   = (float*)(w + 164003840);
    unsigned* bar  = (unsigned*)(w + 164004864);

    // zero h0 epoch-tagged buffers (tag 0 = h(-1)) + bn accumulators + bnp + bar
    hipMemsetAsync(w + 163840000, 0, 166912, stream);

    k_dk<<<dim3(315), dim3(256), 0, stream>>>(dcls_w, dcls_p, dk);
    k_ema<<<dim3(1088), dim3(256), 0, stream>>>(x, a_vals, w_vals, hp);
    k_conv<<<dim3(4, 10, 32), dim3(256), 0, stream>>>(hp, dk, dcls_b, ybcgt);
    k_bnstat<<<dim3(640), dim3(256), 0, stream>>>(ybcgt, bnsum);
    k_bnfin<<<dim3(1), dim3(64), 0, stream>>>(bnsum, gamma, beta, (float*)(w + 164004352));
    k_tr<<<dim3(16, 10, 32), dim3(256), 0, stream>>>(ybcgt, (float*)(w + 164004352), seqH);
    k_gemm<<<dim3(15, 250), dim3(256), 0, stream>>>(seqH, W_ih, b_ih, xpH);

    {
        const __half* xp_a = xpH;
        void* args[] = {(void*)&xp_a, (void*)&W_hh, (void*)&b_hh, (void*)&fc_w,
                        (void*)&hgu, (void*)&fcpart, (void*)&bar};
        hipLaunchCooperativeKernel((void*)k_gru, dim3(40), dim3(512), args, 0, stream);
    }

    k_fc<<<dim3(125), dim3(256), 0, stream>>>(fcpart, fc_b, (float*)d_out);
}